// Round 9
// baseline (3086.320 us; speedup 1.0000x reference)
//
#include <hip/hip_runtime.h>
#include <hip/hip_bf16.h>
#include <stdint.h>

typedef unsigned short u16;
typedef u16   u16x8 __attribute__((ext_vector_type(8)));
typedef short s16x8 __attribute__((ext_vector_type(8)));
typedef float f32x4 __attribute__((ext_vector_type(4)));

#define TOKENS 51200
#define DMODEL 1024
#define DINNER 2048
#define NSTATE 16
#define SEQLEN 100

// workspace layout (bytes)
#define OFF_XP    0ull          // 51200*1024*2   = 104857600
#define OFF_WCAT  104857600ull  // W2: 4096*1024*2 = 8388608
#define OFF_WB    113246208ull  // 16*2048*2      =     65536
#define OFF_WC    113311744ull  // 16*1024*2      =     32768
#define OFF_BPART 113344512ull  // 16*51200*16*4  =  52428800
#define OFF_BFIN  165773312ull  // 51200*16*4     =   3276800
#define OFF_CBUF  169050112ull  // 51200*16*4
#define OFF_Y     172326912ull  // 51200*16*4     -> total 175603712 bytes

__device__ __forceinline__ u16 f2b(float f) {  // f32 -> bf16 RNE
  uint32_t u = __float_as_uint(f);
  uint32_t r = (u + 0x7fffu + ((u >> 16) & 1u)) >> 16;
  return (u16)r;
}
__device__ __forceinline__ float b2f(u16 u) {
  return __uint_as_float(((uint32_t)u) << 16);
}

#define GLL(gp, lp) __builtin_amdgcn_global_load_lds( \
    (__attribute__((address_space(1))) unsigned int*)(gp), \
    (__attribute__((address_space(3))) unsigned int*)(lp), 16, 0, 0)
#define SB0() __builtin_amdgcn_sched_barrier(0)

// ---------------- prep: XP = bf16(x + pos_emb) ----------------
__global__ void k_prep_x(const float* __restrict__ x, const float* __restrict__ pos,
                         u16* __restrict__ xp) {
  long e = ((long)blockIdx.x * blockDim.x + threadIdx.x) * 8;
  int d = (int)(e & (DMODEL - 1));
  long tok = e >> 10;
  int s = (int)(tok % SEQLEN);
  f32x4 a0 = *(const f32x4*)(x + e);
  f32x4 a1 = *(const f32x4*)(x + e + 4);
  f32x4 p0 = *(const f32x4*)(pos + (size_t)s * DMODEL + d);
  f32x4 p1 = *(const f32x4*)(pos + (size_t)s * DMODEL + d + 4);
  u16x8 o;
  o[0] = f2b(a0[0] + p0[0]); o[1] = f2b(a0[1] + p0[1]);
  o[2] = f2b(a0[2] + p0[2]); o[3] = f2b(a0[3] + p0[3]);
  o[4] = f2b(a1[0] + p1[0]); o[5] = f2b(a1[1] + p1[1]);
  o[6] = f2b(a1[2] + p1[2]); o[7] = f2b(a1[3] + p1[3]);
  *(u16x8*)(xp + e) = o;
}

// ---------------- prep: W2 = bf16 row-interleaved [Win;Wg] (row-major) ----------------
// W2 row r (r = 32j+k): k<16 -> Win[16j+k], else Wg[16j+k-16].
__global__ void k_prep_w(const float* __restrict__ Win, const float* __restrict__ Wg,
                         u16* __restrict__ w2) {
  long e = ((long)blockIdx.x * blockDim.x + threadIdx.x) * 8;  // < 4194304
  int r = (int)(e >> 10), c = (int)(e & 1023);
  int srow = ((r >> 5) << 4) + (r & 15);
  const float* src = ((r & 16) ? Wg : Win) + (size_t)srow * DMODEL + c;
  f32x4 a0 = *(const f32x4*)src;
  f32x4 a1 = *(const f32x4*)(src + 4);
  u16x8 o;
  o[0] = f2b(a0[0]); o[1] = f2b(a0[1]); o[2] = f2b(a0[2]); o[3] = f2b(a0[3]);
  o[4] = f2b(a1[0]); o[5] = f2b(a1[1]); o[6] = f2b(a1[2]); o[7] = f2b(a1[3]);
  *(u16x8*)(w2 + e) = o;
}

// ---------------- prep: W_B, W_C -> bf16 ----------------
__global__ void k_prep_wbc(const float* __restrict__ WB, const float* __restrict__ WC,
                           u16* __restrict__ wb, u16* __restrict__ wc) {
  long e = ((long)blockIdx.x * blockDim.x + threadIdx.x) * 8;  // < 49152
  const float* src; u16* dst;
  if (e < 32768) { src = WB + e; dst = wb + e; }
  else           { src = WC + (e - 32768); dst = wc + (e - 32768); }
  f32x4 a0 = *(const f32x4*)src;
  f32x4 a1 = *(const f32x4*)(src + 4);
  u16x8 o;
  o[0] = f2b(a0[0]); o[1] = f2b(a0[1]); o[2] = f2b(a0[2]); o[3] = f2b(a0[3]);
  o[4] = f2b(a1[0]); o[5] = f2b(a1[1]); o[6] = f2b(a1[2]); o[7] = f2b(a1[3]);
  *(u16x8*)(dst) = o;
}

// ============ fused dual GEMM: 256x256, BK=32, 2 blocks/CU (occupancy lever) ============
// 512 threads = 8 waves (2M x 4N), per-wave C = 128x64 (acc[8][4] 16x16x32 frags).
// LDS 68KB alloc: main loop 2 bufs x {A 16KB, B 16KB} = 64KB; epilogue xg needs 68KB.
// -> 2 blocks/CU (136KB <= 160KB), 4 waves/SIMD: cross-block TLP hides barrier/waitcnt.
// Per tile: vmcnt(4) counted; read A-lo+B (8); 16 MFMA; read A-hi (4); lgkm0+barrier;
// stage t+2 (4 GLL) interleaved with 2x8 MFMA. Rows are 64B; swizzle chunk^=((l15>>1)&3).
__global__ __launch_bounds__(512, 4) void k_gemm256(
    const u16* __restrict__ XP, const u16* __restrict__ W2, const u16* __restrict__ WBb,
    const float* __restrict__ b_in, const float* __restrict__ b_gate,
    float* __restrict__ Bpart) {
  extern __shared__ __align__(16) u16 smem[];
  char* smemc = (char*)smem;

  const int tid = threadIdx.x;
  const int bid = blockIdx.x;
  // M-partitioned XCD mapping (bijective over 3200 = 8 XCD x 25 rb x 16 nb)
  const int xcd = bid & 7;
  const int q   = bid >> 3;            // 0..399
  const int rb  = xcd * 25 + (q >> 4); // 0..199
  const int nb  = q & 15;              // 0..15
  const int m0 = rb << 8;
  const int n0 = nb << 8;

  // --- staging: row = tid>>2 (0..127, +128 round 1), chunk (tid&3) inverse-swizzled ---
  const int srow = tid >> 2;                                   // 0..127
  const int csrc = ((tid & 3) ^ ((tid >> 3) & 3)) << 3;        // element offset in row
  const u16* gA = XP + (size_t)(m0 + srow) * DMODEL + csrc;
  const u16* gB = W2 + (size_t)(n0 + srow) * DMODEL + csrc;
  const int ldst = tid << 3;                                   // u16 offset (16B/thread)

  // --- wave/frag constants ---
  const int wid = tid >> 6, lane = tid & 63;
  const int wm = wid >> 2, wn = wid & 3;
  const int l15 = lane & 15, lhi = lane >> 4;
  const int kchunk = (lhi ^ ((l15 >> 1) & 3)) << 4;            // swizzled 16B chunk (byte)
  const int arow0 = (wm << 7) + l15;
  const int brow0 = (wn << 6) + l15;

  auto rdA = [&](int bufb, int m) -> s16x8 {
    return *(const s16x8*)(smemc + bufb + ((arow0 + (m << 4)) << 6) + kchunk);
  };
  auto rdB = [&](int bufb, int n) -> s16x8 {
    return *(const s16x8*)(smemc + bufb + 16384 + ((brow0 + (n << 4)) << 6) + kchunk);
  };
  // stage one matrix of tile t: 2 GLLs (rows 0..127, 128..255)
  auto stgA = [&](int t) {
    const int bb = (t & 1) << 14;                // u16 offset of buffer (32KB)
    const u16* g_ = gA + ((size_t)t << 5);
    GLL(g_,           smem + bb + ldst);
    GLL(g_ + 131072,  smem + bb + 4096 + ldst);
  };
  auto stgB = [&](int t) {
    const int bb = (t & 1) << 14;
    const u16* g_ = gB + ((size_t)t << 5);
    GLL(g_,           smem + bb + 8192 + ldst);
    GLL(g_ + 131072,  smem + bb + 8192 + 4096 + ldst);
  };

  f32x4 acc[8][4] = {};

  // prologue: stage tiles 0 and 1 (FIFO groups of 4: A(0),B(0),A(1),B(1))
  stgA(0); stgB(0); stgA(1); stgB(1);

#pragma unroll 1
  for (int t = 0; t < 32; ++t) {
    if (t == 31) asm volatile("s_waitcnt vmcnt(0)" ::: "memory");
    else         asm volatile("s_waitcnt vmcnt(4)" ::: "memory");
    SB0();
    asm volatile("s_barrier" ::: "memory");
    SB0();
    const int bufb = (t & 1) << 15;  // byte offset

    s16x8 afl[4], afh[4], bfr[4];
    // ---- reads A-lo + B; 16 MFMA (m0-3 x n0-3) ----
#pragma unroll
    for (int m = 0; m < 4; ++m) afl[m] = rdA(bufb, m);
#pragma unroll
    for (int n = 0; n < 4; ++n) bfr[n] = rdB(bufb, n);
    __builtin_amdgcn_s_setprio(1);
#pragma unroll
    for (int m = 0; m < 4; ++m)
#pragma unroll
      for (int n = 0; n < 4; ++n)
        acc[m][n] = __builtin_amdgcn_mfma_f32_16x16x32_bf16(afl[m], bfr[n], acc[m][n], 0, 0, 0);
    __builtin_amdgcn_s_setprio(0);

    // ---- A-hi frags; mid-tile buffer-free proof ----
#pragma unroll
    for (int m = 0; m < 4; ++m) afh[m] = rdA(bufb, m + 4);
    asm volatile("s_waitcnt lgkmcnt(0)" ::: "memory");
    SB0();
    asm volatile("s_barrier" ::: "memory");
    SB0();

    // ---- post-mid: 2 MFMA clusters (8/8) with staging slots between ----
    if (t < 30) stgA(t + 2);
    SB0();
    __builtin_amdgcn_s_setprio(1);
#pragma unroll
    for (int m = 0; m < 4; ++m)
#pragma unroll
      for (int n = 0; n < 2; ++n)
        acc[m + 4][n] = __builtin_amdgcn_mfma_f32_16x16x32_bf16(afh[m], bfr[n], acc[m + 4][n], 0, 0, 0);
    __builtin_amdgcn_s_setprio(0);
    SB0();
    if (t < 30) stgB(t + 2);
    SB0();
    __builtin_amdgcn_s_setprio(1);
#pragma unroll
    for (int m = 0; m < 4; ++m)
#pragma unroll
      for (int n = 2; n < 4; ++n)
        acc[m + 4][n] = __builtin_amdgcn_mfma_f32_16x16x32_bf16(afh[m], bfr[n], acc[m + 4][n], 0, 0, 0);
    __builtin_amdgcn_s_setprio(0);
    SB0();
  }

  // close the loop: all waves done reading before epilogue overwrites LDS
  asm volatile("s_waitcnt lgkmcnt(0)" ::: "memory");
  SB0();
  asm volatile("s_barrier" ::: "memory");
  SB0();

  // --- epilogue: in-register gating (acc[m][2u]=proj, acc[m][2u+1]=gate) ---
  u16* xg = smem;  // [256][136] bf16 (+8 pad), 69632 B
  float bi[2], bg[2];
#pragma unroll
  for (int u = 0; u < 2; ++u) {
    const int gcol = (nb << 7) + (((wn << 1) + u) << 4) + l15;
    bi[u] = b_in[gcol];
    bg[u] = b_gate[gcol];
  }
#pragma unroll
  for (int m = 0; m < 8; ++m)
#pragma unroll
    for (int u = 0; u < 2; ++u)
#pragma unroll
      for (int j = 0; j < 4; ++j) {
        const int row = (wm << 7) + (m << 4) + (lhi << 2) + j;
        const int col = (((wn << 1) + u) << 4) + l15;
        float pv = acc[m][2 * u][j] + bi[u];
        float gv = acc[m][2 * u + 1][j] + bg[u];
        xg[row * 136 + col] = f2b(pv / (1.0f + __expf(-gv)));
      }
  asm volatile("s_waitcnt lgkmcnt(0)" ::: "memory");
  asm volatile("s_barrier" ::: "memory");

  // --- mini-GEMM: Bpart[nb][m0+row][state] = xg @ W_B[:, nb*128..+128]^T ---
  f32x4 bacc[2] = {};
#pragma unroll
  for (int m2 = 0; m2 < 2; ++m2)
#pragma unroll
    for (int kc = 0; kc < 4; ++kc) {
      s16x8 av = *(const s16x8*)(xg + ((wid << 5) + (m2 << 4) + l15) * 136 + (kc << 5) + (lhi << 3));
      s16x8 bv = *(const s16x8*)(WBb + (size_t)l15 * DINNER + (nb << 7) + (kc << 5) + (lhi << 3));
      bacc[m2] = __builtin_amdgcn_mfma_f32_16x16x32_bf16(av, bv, bacc[m2], 0, 0, 0);
    }
#pragma unroll
  for (int m2 = 0; m2 < 2; ++m2) {
    float* outp = Bpart + ((size_t)nb * TOKENS + m0 + (wid << 5) + (m2 << 4) + (lhi << 2)) * NSTATE + l15;
#pragma unroll
    for (int j = 0; j < 4; ++j) outp[j * NSTATE] = bacc[m2][j];
  }
}

// ---------------- C = XP @ W_C^T + b_C (MFMA; W_C staged once in LDS) ----------------
__global__ __launch_bounds__(256) void k_C(const u16* __restrict__ XP, const u16* __restrict__ WC,
                                           const float* __restrict__ bC, float* __restrict__ Cb) {
  __shared__ __align__(16) u16 wcl[16 * 1032];  // rows padded +8 elems
  const int tid = threadIdx.x;
  const int m0 = blockIdx.x << 6;
#pragma unroll
  for (int i = 0; i < 8; ++i) {
    int c = i * 256 + tid;                       // 16B chunk id, 0..2047
    int row = c >> 7, col = c & 127;
    *(u16x8*)(wcl + row * 1032 + (col << 3)) = *(const u16x8*)(WC + (row << 10) + (col << 3));
  }
  __syncthreads();
  const int wv = tid >> 6, lane = tid & 63;
  const int l15 = lane & 15, lhi = lane >> 4;
  const u16* xr = XP + (size_t)(m0 + (wv << 4) + l15) * DMODEL + (lhi << 3);
  const u16* wr = wcl + l15 * 1032 + (lhi << 3);
  f32x4 acc = {};
#pragma unroll
  for (int t = 0; t < 32; ++t) {
    s16x8 av = *(const s16x8*)(xr + t * 32);
    s16x8 bv = *(const s16x8*)(wr + t * 32);
    acc = __builtin_amdgcn_mfma_f32_16x16x32_bf16(av, bv, acc, 0, 0, 0);
  }
  const float bc = bC[l15];
  float* o = Cb + (size_t)(m0 + (wv << 4) + (lhi << 2)) * NSTATE + l15;
#pragma unroll
  for (int j = 0; j < 4; ++j) o[j * NSTATE] = acc[j] + bc;
}

// ---------------- B = sum_chunks Bpart + b_B ----------------
__global__ void k_finB(const float* __restrict__ Bpart, const float* __restrict__ bB,
                       float* __restrict__ Bf) {
  const long i = (long)blockIdx.x * blockDim.x + threadIdx.x;  // per float4
  f32x4 s = {};
#pragma unroll
  for (int cb = 0; cb < 16; ++cb)
    s += *(const f32x4*)(Bpart + (size_t)cb * (TOKENS * NSTATE) + i * 4);
  s += *(const f32x4*)(bB + ((i & 3) << 2));
  *(f32x4*)(Bf + i * 4) = s;
}

// ---------------- sequential scan: h = A*h + B; y = h*C ----------------
__global__ void k_scan(const float* __restrict__ Bf, const float* __restrict__ Cb,
                       const float* __restrict__ Alog, float* __restrict__ Y) {
  const int t = threadIdx.x;
  const int b = blockIdx.x * 16 + (t >> 4);
  const int n = t & 15;
  const float A = __expf(0.01f * __expf(Alog[n]));
  float h = 0.f;
  const size_t base = (size_t)b * SEQLEN * NSTATE + n;
  for (int s = 0; s < SEQLEN; ++s) {
    const size_t idx = base + (size_t)s * NSTATE;
    h = A * h + Bf[idx];
    Y[idx] = h * Cb[idx];
  }
}

// ---------------- out = Y @ W_out[:, :16]^T + b_out ----------------
__global__ __launch_bounds__(256) void k_out(const float* __restrict__ Y,
                                             const float* __restrict__ Wout,
                                             const float* __restrict__ bout,
                                             float* __restrict__ out) {
  __shared__ float ys[32][16];
  const int tid = threadIdx.x;
  const long t0 = (long)blockIdx.x * 32;
  for (int i = tid; i < 512; i += 256) ys[i >> 4][i & 15] = Y[t0 * 16 + i];
  const int d0 = tid << 2;
  float w[4][16];
#pragma unroll
  for (int j = 0; j < 4; ++j)
#pragma unroll
    for (int q = 0; q < 4; ++q) {
      f32x4 wv = *(const f32x4*)(Wout + (size_t)(d0 + j) * DINNER + q * 4);
#pragma unroll
      for (int e = 0; e < 4; ++e) w[j][q * 4 + e] = wv[e];
    }
  f32x4 bo = *(const f32x4*)(bout + d0);
  __syncthreads();
  for (int r = 0; r < 32; ++r) {
    f32x4 acc = bo;
#pragma unroll
    for (int n = 0; n < 16; ++n) {
      const float yv = ys[r][n];
      acc[0] += yv * w[0][n];
      acc[1] += yv * w[1][n];
      acc[2] += yv * w[2][n];
      acc[3] += yv * w[3][n];
    }
    *(f32x4*)(out + (t0 + r) * 1024 + d0) = acc;
  }
}

extern "C" void kernel_launch(void* const* d_in, const int* in_sizes, int n_in,
                              void* d_out, int out_size, void* d_ws, size_t ws_size,
                              hipStream_t stream) {
  const float* x    = (const float*)d_in[0];
  const float* pos  = (const float*)d_in[1];
  const float* Win  = (const float*)d_in[2];
  const float* bin  = (const float*)d_in[3];
  const float* Wg   = (const float*)d_in[4];
  const float* bg   = (const float*)d_in[5];
  const float* Alog = (const float*)d_in[6];
  const float* WB   = (const float*)d_in[7];
  const float* bB   = (const float*)d_in[8];
  const float* WC   = (const float*)d_in[9];
  const float* bC   = (const float*)d_in[10];
  const float* Wout = (const float*)d_in[11];
  const float* bout = (const float*)d_in[12];

  char* ws = (char*)d_ws;
  u16*   XP   = (u16*)(ws + OFF_XP);
  u16*   W2   = (u16*)(ws + OFF_WCAT);
  u16*   WBb  = (u16*)(ws + OFF_WB);
  u16*   WCb  = (u16*)(ws + OFF_WC);
  float* BP   = (float*)(ws + OFF_BPART);
  float* BF   = (float*)(ws + OFF_BFIN);
  float* CB   = (float*)(ws + OFF_CBUF);
  float* Yb   = (float*)(ws + OFF_Y);

  hipFuncSetAttribute((const void*)k_gemm256,
                      hipFuncAttributeMaxDynamicSharedMemorySize, 69632);

  k_prep_x  <<<25600, 256, 0, stream>>>(x, pos, XP);
  k_prep_w  <<<2048, 256, 0, stream>>>(Win, Wg, W2);
  k_prep_wbc<<<24, 256, 0, stream>>>(WB, WC, WBb, WCb);
  k_gemm256 <<<3200, 512, 69632, stream>>>(XP, W2, WBb, bin, bg, BP);
  k_C       <<<800, 256, 0, stream>>>(XP, WCb, bC, CB);
  k_finB    <<<800, 256, 0, stream>>>(BP, bB, BF);
  k_scan    <<<32, 256, 0, stream>>>(BF, CB, Alog, Yb);
  k_out     <<<1600, 256, 0, stream>>>(Yb, Wout, bout, (float*)d_out);
}

// Round 11
// 607.015 us; speedup vs baseline: 5.0844x; 5.0844x over previous
//
#include <hip/hip_runtime.h>
#include <hip/hip_bf16.h>
#include <stdint.h>

typedef unsigned short u16;
typedef u16   u16x8 __attribute__((ext_vector_type(8)));
typedef short s16x8 __attribute__((ext_vector_type(8)));
typedef float f32x4 __attribute__((ext_vector_type(4)));

#define TOKENS 51200
#define DMODEL 1024
#define DINNER 2048
#define NSTATE 16
#define SEQLEN 100

// workspace layout (bytes)
#define OFF_XP    0ull          // 51200*1024*2   = 104857600
#define OFF_WCAT  104857600ull  // W2: 4096*1024*2 = 8388608
#define OFF_WB    113246208ull  // 16*2048*2      =     65536
#define OFF_WC    113311744ull  // 16*1024*2      =     32768
#define OFF_BPART 113344512ull  // 16*51200*16*4  =  52428800
#define OFF_BFIN  165773312ull  // 51200*16*4     =   3276800
#define OFF_CBUF  169050112ull  // 51200*16*4
#define OFF_Y     172326912ull  // 51200*16*4     -> total 175603712 bytes

__device__ __forceinline__ u16 f2b(float f) {  // f32 -> bf16 RNE
  uint32_t u = __float_as_uint(f);
  uint32_t r = (u + 0x7fffu + ((u >> 16) & 1u)) >> 16;
  return (u16)r;
}
__device__ __forceinline__ float b2f(u16 u) {
  return __uint_as_float(((uint32_t)u) << 16);
}

#define GLL(gp, lp) __builtin_amdgcn_global_load_lds( \
    (__attribute__((address_space(1))) unsigned int*)(gp), \
    (__attribute__((address_space(3))) unsigned int*)(lp), 16, 0, 0)
#define SB0() __builtin_amdgcn_sched_barrier(0)

// ---------------- prep: XP = bf16(x + pos_emb) ----------------
__global__ void k_prep_x(const float* __restrict__ x, const float* __restrict__ pos,
                         u16* __restrict__ xp) {
  long e = ((long)blockIdx.x * blockDim.x + threadIdx.x) * 8;
  int d = (int)(e & (DMODEL - 1));
  long tok = e >> 10;
  int s = (int)(tok % SEQLEN);
  f32x4 a0 = *(const f32x4*)(x + e);
  f32x4 a1 = *(const f32x4*)(x + e + 4);
  f32x4 p0 = *(const f32x4*)(pos + (size_t)s * DMODEL + d);
  f32x4 p1 = *(const f32x4*)(pos + (size_t)s * DMODEL + d + 4);
  u16x8 o;
  o[0] = f2b(a0[0] + p0[0]); o[1] = f2b(a0[1] + p0[1]);
  o[2] = f2b(a0[2] + p0[2]); o[3] = f2b(a0[3] + p0[3]);
  o[4] = f2b(a1[0] + p1[0]); o[5] = f2b(a1[1] + p1[1]);
  o[6] = f2b(a1[2] + p1[2]); o[7] = f2b(a1[3] + p1[3]);
  *(u16x8*)(xp + e) = o;
}

// ---------------- prep: W2 = bf16 row-interleaved [Win;Wg] (row-major) ----------------
// W2 row r (r = 32j+k): k<16 -> Win[16j+k], else Wg[16j+k-16].
__global__ void k_prep_w(const float* __restrict__ Win, const float* __restrict__ Wg,
                         u16* __restrict__ w2) {
  long e = ((long)blockIdx.x * blockDim.x + threadIdx.x) * 8;  // < 4194304
  int r = (int)(e >> 10), c = (int)(e & 1023);
  int srow = ((r >> 5) << 4) + (r & 15);
  const float* src = ((r & 16) ? Wg : Win) + (size_t)srow * DMODEL + c;
  f32x4 a0 = *(const f32x4*)src;
  f32x4 a1 = *(const f32x4*)(src + 4);
  u16x8 o;
  o[0] = f2b(a0[0]); o[1] = f2b(a0[1]); o[2] = f2b(a0[2]); o[3] = f2b(a0[3]);
  o[4] = f2b(a1[0]); o[5] = f2b(a1[1]); o[6] = f2b(a1[2]); o[7] = f2b(a1[3]);
  *(u16x8*)(w2 + e) = o;
}

// ---------------- prep: W_B, W_C -> bf16 ----------------
__global__ void k_prep_wbc(const float* __restrict__ WB, const float* __restrict__ WC,
                           u16* __restrict__ wb, u16* __restrict__ wc) {
  long e = ((long)blockIdx.x * blockDim.x + threadIdx.x) * 8;  // < 49152
  const float* src; u16* dst;
  if (e < 32768) { src = WB + e; dst = wb + e; }
  else           { src = WC + (e - 32768); dst = wc + (e - 32768); }
  f32x4 a0 = *(const f32x4*)src;
  f32x4 a1 = *(const f32x4*)(src + 4);
  u16x8 o;
  o[0] = f2b(a0[0]); o[1] = f2b(a0[1]); o[2] = f2b(a0[2]); o[3] = f2b(a0[3]);
  o[4] = f2b(a1[0]); o[5] = f2b(a1[1]); o[6] = f2b(a1[2]); o[7] = f2b(a1[3]);
  *(u16x8*)(dst) = o;
}

// ============ fused dual GEMM: 128x256 tile, BK=32, acc[4][4] -> 2 blocks/CU ============
// 512 threads = 8 waves (2M x 4N), per-wave C = 64x64 (acc[4][4] = 64 AGPR).
// Regs ~124/wave (<=128) -> 4 waves/SIMD. LDS 64KB alloc (2 bufs x {A 8KB, B 16KB}),
// 2 blocks/CU: independent blocks cover each other's barrier/waitcnt stalls (m114).
// Per tile: vmcnt(3) counted; read a[4],b[4]; 8 MFMA; lgkm0+barrier; stage t+2 (3 GLL); 8 MFMA.
// LDS u16 map per buffer (bb=(t&1)<<14): A [0,4096) ; B rows0-127 [4096,8192) ; B rows128-255 [8192,12288).
__global__ __launch_bounds__(512, 4) void k_gemm256(
    const u16* __restrict__ XP, const u16* __restrict__ W2, const u16* __restrict__ WBb,
    const float* __restrict__ b_in, const float* __restrict__ b_gate,
    float* __restrict__ Bpart) {
  extern __shared__ __align__(16) u16 smem[];
  char* smemc = (char*)smem;

  const int tid = threadIdx.x;
  const int bid = blockIdx.x;
  // M-partitioned XCD mapping (bijective over 6400 = 8 XCD x 50 rb x 16 nb)
  const int xcd = bid & 7;
  const int q   = bid >> 3;            // 0..799
  const int rb  = xcd * 50 + (q >> 4); // 0..399
  const int nb  = q & 15;              // 0..15
  const int m0 = rb << 7;              // 128 rows/block
  const int n0 = nb << 8;              // 256 combined cols/block

  // --- staging: row = tid>>2 (0..127), chunk (tid&3) inverse-swizzled: ^=(row>>1)&3 ---
  const int srow = tid >> 2;
  const int csrc = ((tid & 3) ^ ((tid >> 3) & 3)) << 3;        // element offset in row
  const u16* gA = XP + (size_t)(m0 + srow) * DMODEL + csrc;
  const u16* gB = W2 + (size_t)(n0 + srow) * DMODEL + csrc;
  const int ldst = tid << 3;                                   // u16 offset (16B/thread)

  // --- wave/frag constants ---
  const int wid = tid >> 6, lane = tid & 63;
  const int wm = wid >> 2, wn = wid & 3;
  const int l15 = lane & 15, lhi = lane >> 4;
  const int arow0 = (wm << 6) + l15;                           // wave M span 64
  const int brow0 = (wn << 6) + l15;                           // wave N span 64
  const int kchA = (lhi ^ ((arow0 >> 1) & 3)) << 4;            // swizzled 16B chunk (byte)
  const int kchB = (lhi ^ ((brow0 >> 1) & 3)) << 4;

  auto rdA = [&](int bufb, int m) -> s16x8 {   // rows 64B apart
    return *(const s16x8*)(smemc + bufb + ((arow0 + (m << 4)) << 6) + kchA);
  };
  auto rdB = [&](int bufb, int n) -> s16x8 {
    return *(const s16x8*)(smemc + bufb + 8192 + ((brow0 + (n << 4)) << 6) + kchB);
  };
  // stage tile t: A 1 GLL (128 rows x 64B), B 2 GLLs (rows 0-127, 128-255); 3 GLL total
  auto stage = [&](int t) {
    const int bb = (t & 1) << 14;                // u16 offset of buffer
    const u16* a_ = gA + ((size_t)t << 5);
    const u16* b_ = gB + ((size_t)t << 5);
    GLL(a_,          smem + bb + ldst);
    GLL(b_,          smem + bb + 4096 + ldst);
    GLL(b_ + 131072, smem + bb + 8192 + ldst);   // FIX (was +4096+2048)
  };

  f32x4 acc[4][4] = {};

  // prologue: stage tiles 0,1 (FIFO: 3+3)
  stage(0); stage(1);

#pragma unroll 1
  for (int t = 0; t < 32; ++t) {
    if (t == 31) asm volatile("s_waitcnt vmcnt(0)" ::: "memory");
    else         asm volatile("s_waitcnt vmcnt(3)" ::: "memory");
    SB0();
    asm volatile("s_barrier" ::: "memory");
    SB0();
    const int bufb = (t & 1) << 15;  // byte offset

    s16x8 a[4], b[4];
#pragma unroll
    for (int m = 0; m < 4; ++m) a[m] = rdA(bufb, m);
#pragma unroll
    for (int n = 0; n < 4; ++n) b[n] = rdB(bufb, n);

    __builtin_amdgcn_s_setprio(1);
#pragma unroll
    for (int m = 0; m < 4; ++m)
#pragma unroll
      for (int n = 0; n < 2; ++n)
        acc[m][n] = __builtin_amdgcn_mfma_f32_16x16x32_bf16(a[m], b[n], acc[m][n], 0, 0, 0);
    __builtin_amdgcn_s_setprio(0);

    asm volatile("s_waitcnt lgkmcnt(0)" ::: "memory");
    SB0();
    asm volatile("s_barrier" ::: "memory");
    SB0();
    if (t < 30) stage(t + 2);
    SB0();

    __builtin_amdgcn_s_setprio(1);
#pragma unroll
    for (int m = 0; m < 4; ++m)
#pragma unroll
      for (int n = 2; n < 4; ++n)
        acc[m][n] = __builtin_amdgcn_mfma_f32_16x16x32_bf16(a[m], b[n], acc[m][n], 0, 0, 0);
    __builtin_amdgcn_s_setprio(0);
  }

  // all reads done before epilogue overwrites LDS
  asm volatile("s_waitcnt lgkmcnt(0)" ::: "memory");
  SB0();
  asm volatile("s_barrier" ::: "memory");
  SB0();

  // --- epilogue: in-register gating (acc[m][2u]=proj, acc[m][2u+1]=gate) ---
  u16* xg = smem;  // [128][136] bf16 (+8 pad), 34816 B
  float bi[2], bg[2];
#pragma unroll
  for (int u = 0; u < 2; ++u) {
    const int gcol = (nb << 7) + (((wn << 1) + u) << 4) + l15;
    bi[u] = b_in[gcol];
    bg[u] = b_gate[gcol];
  }
#pragma unroll
  for (int m = 0; m < 4; ++m)
#pragma unroll
    for (int u = 0; u < 2; ++u)
#pragma unroll
      for (int j = 0; j < 4; ++j) {
        const int row = (wm << 6) + (m << 4) + (lhi << 2) + j;
        const int col = (((wn << 1) + u) << 4) + l15;
        float pv = acc[m][2 * u][j] + bi[u];
        float gv = acc[m][2 * u + 1][j] + bg[u];
        xg[row * 136 + col] = f2b(pv / (1.0f + __expf(-gv)));
      }
  asm volatile("s_waitcnt lgkmcnt(0)" ::: "memory");
  asm volatile("s_barrier" ::: "memory");

  // --- mini-GEMM: Bpart[nb][m0+row][state] = xg @ W_B[:, nb*128..+128]^T ---
  // 8 waves x 16 rows = 128 rows; 4 MFMAs per wave over K=128
  f32x4 bacc = {};
#pragma unroll
  for (int kc = 0; kc < 4; ++kc) {
    s16x8 av = *(const s16x8*)(xg + ((wid << 4) + l15) * 136 + (kc << 5) + (lhi << 3));
    s16x8 bv = *(const s16x8*)(WBb + (size_t)l15 * DINNER + (nb << 7) + (kc << 5) + (lhi << 3));
    bacc = __builtin_amdgcn_mfma_f32_16x16x32_bf16(av, bv, bacc, 0, 0, 0);
  }
  float* outp = Bpart + ((size_t)nb * TOKENS + m0 + (wid << 4) + (lhi << 2)) * NSTATE + l15;
#pragma unroll
  for (int j = 0; j < 4; ++j) outp[j * NSTATE] = bacc[j];
}

// ---------------- C = XP @ W_C^T + b_C (MFMA; W_C staged once in LDS) ----------------
__global__ __launch_bounds__(256) void k_C(const u16* __restrict__ XP, const u16* __restrict__ WC,
                                           const float* __restrict__ bC, float* __restrict__ Cb) {
  __shared__ __align__(16) u16 wcl[16 * 1032];  // rows padded +8 elems
  const int tid = threadIdx.x;
  const int m0 = blockIdx.x << 6;
#pragma unroll
  for (int i = 0; i < 8; ++i) {
    int c = i * 256 + tid;                       // 16B chunk id, 0..2047
    int row = c >> 7, col = c & 127;
    *(u16x8*)(wcl + row * 1032 + (col << 3)) = *(const u16x8*)(WC + (row << 10) + (col << 3));
  }
  __syncthreads();
  const int wv = tid >> 6, lane = tid & 63;
  const int l15 = lane & 15, lhi = lane >> 4;
  const u16* xr = XP + (size_t)(m0 + (wv << 4) + l15) * DMODEL + (lhi << 3);
  const u16* wr = wcl + l15 * 1032 + (lhi << 3);
  f32x4 acc = {};
#pragma unroll
  for (int t = 0; t < 32; ++t) {
    s16x8 av = *(const s16x8*)(xr + t * 32);
    s16x8 bv = *(const s16x8*)(wr + t * 32);
    acc = __builtin_amdgcn_mfma_f32_16x16x32_bf16(av, bv, acc, 0, 0, 0);
  }
  const float bc = bC[l15];
  float* o = Cb + (size_t)(m0 + (wv << 4) + (lhi << 2)) * NSTATE + l15;
#pragma unroll
  for (int j = 0; j < 4; ++j) o[j * NSTATE] = acc[j] + bc;
}

// ---------------- B = sum_chunks Bpart + b_B ----------------
__global__ void k_finB(const float* __restrict__ Bpart, const float* __restrict__ bB,
                       float* __restrict__ Bf) {
  const long i = (long)blockIdx.x * blockDim.x + threadIdx.x;  // per float4
  f32x4 s = {};
#pragma unroll
  for (int cb = 0; cb < 16; ++cb)
    s += *(const f32x4*)(Bpart + (size_t)cb * (TOKENS * NSTATE) + i * 4);
  s += *(const f32x4*)(bB + ((i & 3) << 2));
  *(f32x4*)(Bf + i * 4) = s;
}

// ---------------- sequential scan: h = A*h + B; y = h*C ----------------
__global__ void k_scan(const float* __restrict__ Bf, const float* __restrict__ Cb,
                       const float* __restrict__ Alog, float* __restrict__ Y) {
  const int t = threadIdx.x;
  const int b = blockIdx.x * 16 + (t >> 4);
  const int n = t & 15;
  const float A = __expf(0.01f * __expf(Alog[n]));
  float h = 0.f;
  const size_t base = (size_t)b * SEQLEN * NSTATE + n;
  for (int s = 0; s < SEQLEN; ++s) {
    const size_t idx = base + (size_t)s * NSTATE;
    h = A * h + Bf[idx];
    Y[idx] = h * Cb[idx];
  }
}

// ---------------- out = Y @ W_out[:, :16]^T + b_out ----------------
__global__ __launch_bounds__(256) void k_out(const float* __restrict__ Y,
                                             const float* __restrict__ Wout,
                                             const float* __restrict__ bout,
                                             float* __restrict__ out) {
  __shared__ float ys[32][16];
  const int tid = threadIdx.x;
  const long t0 = (long)blockIdx.x * 32;
  for (int i = tid; i < 512; i += 256) ys[i >> 4][i & 15] = Y[t0 * 16 + i];
  const int d0 = tid << 2;
  float w[4][16];
#pragma unroll
  for (int j = 0; j < 4; ++j)
#pragma unroll
    for (int q = 0; q < 4; ++q) {
      f32x4 wv = *(const f32x4*)(Wout + (size_t)(d0 + j) * DINNER + q * 4);
#pragma unroll
      for (int e = 0; e < 4; ++e) w[j][q * 4 + e] = wv[e];
    }
  f32x4 bo = *(const f32x4*)(bout + d0);
  __syncthreads();
  for (int r = 0; r < 32; ++r) {
    f32x4 acc = bo;
#pragma unroll
    for (int n = 0; n < 16; ++n) {
      const float yv = ys[r][n];
      acc[0] += yv * w[0][n];
      acc[1] += yv * w[1][n];
      acc[2] += yv * w[2][n];
      acc[3] += yv * w[3][n];
    }
    *(f32x4*)(out + (t0 + r) * 1024 + d0) = acc;
  }
}

extern "C" void kernel_launch(void* const* d_in, const int* in_sizes, int n_in,
                              void* d_out, int out_size, void* d_ws, size_t ws_size,
                              hipStream_t stream) {
  const float* x    = (const float*)d_in[0];
  const float* pos  = (const float*)d_in[1];
  const float* Win  = (const float*)d_in[2];
  const float* bin  = (const float*)d_in[3];
  const float* Wg   = (const float*)d_in[4];
  const float* bg   = (const float*)d_in[5];
  const float* Alog = (const float*)d_in[6];
  const float* WB   = (const float*)d_in[7];
  const float* bB   = (const float*)d_in[8];
  const float* WC   = (const float*)d_in[9];
  const float* bC   = (const float*)d_in[10];
  const float* Wout = (const float*)d_in[11];
  const float* bout = (const float*)d_in[12];

  char* ws = (char*)d_ws;
  u16*   XP   = (u16*)(ws + OFF_XP);
  u16*   W2   = (u16*)(ws + OFF_WCAT);
  u16*   WBb  = (u16*)(ws + OFF_WB);
  u16*   WCb  = (u16*)(ws + OFF_WC);
  float* BP   = (float*)(ws + OFF_BPART);
  float* BF   = (float*)(ws + OFF_BFIN);
  float* CB   = (float*)(ws + OFF_CBUF);
  float* Yb   = (float*)(ws + OFF_Y);

  hipFuncSetAttribute((const void*)k_gemm256,
                      hipFuncAttributeMaxDynamicSharedMemorySize, 65536);

  k_prep_x  <<<25600, 256, 0, stream>>>(x, pos, XP);
  k_prep_w  <<<2048, 256, 0, stream>>>(Win, Wg, W2);
  k_prep_wbc<<<24, 256, 0, stream>>>(WB, WC, WBb, WCb);
  k_gemm256 <<<6400, 512, 65536, stream>>>(XP, W2, WBb, bin, bg, BP);
  k_C       <<<800, 256, 0, stream>>>(XP, WCb, bC, CB);
  k_finB    <<<800, 256, 0, stream>>>(BP, bB, BF);
  k_scan    <<<32, 256, 0, stream>>>(BF, CB, Alog, Yb);
  k_out     <<<1600, 256, 0, stream>>>(Yb, Wout, bout, (float*)d_out);
}

// Round 12
// 605.753 us; speedup vs baseline: 5.0950x; 1.0021x over previous
//
#include <hip/hip_runtime.h>
#include <hip/hip_bf16.h>
#include <stdint.h>

typedef unsigned short u16;
typedef u16   u16x8 __attribute__((ext_vector_type(8)));
typedef short s16x8 __attribute__((ext_vector_type(8)));
typedef float f32x4 __attribute__((ext_vector_type(4)));

#define TOKENS 51200
#define DMODEL 1024
#define DINNER 2048
#define NSTATE 16
#define SEQLEN 100

// workspace layout (bytes)
#define OFF_XP    0ull          // 51200*1024*2   = 104857600
#define OFF_WCAT  104857600ull  // W2: 4096*1024*2 = 8388608
#define OFF_WB    113246208ull  // 16*2048*2      =     65536
#define OFF_WC    113311744ull  // 16*1024*2      =     32768
#define OFF_BPART 113344512ull  // 16*51200*16*4  =  52428800
#define OFF_BFIN  165773312ull  // 51200*16*4     =   3276800
#define OFF_CBUF  169050112ull  // 51200*16*4
#define OFF_Y     172326912ull  // 51200*16*4     -> total 175603712 bytes

__device__ __forceinline__ u16 f2b(float f) {  // f32 -> bf16 RNE
  uint32_t u = __float_as_uint(f);
  uint32_t r = (u + 0x7fffu + ((u >> 16) & 1u)) >> 16;
  return (u16)r;
}
__device__ __forceinline__ float b2f(u16 u) {
  return __uint_as_float(((uint32_t)u) << 16);
}

#define GLL(gp, lp) __builtin_amdgcn_global_load_lds( \
    (__attribute__((address_space(1))) unsigned int*)(gp), \
    (__attribute__((address_space(3))) unsigned int*)(lp), 16, 0, 0)
#define SB0() __builtin_amdgcn_sched_barrier(0)

// ---------------- prep: XP = bf16(x + pos_emb) ----------------
__global__ void k_prep_x(const float* __restrict__ x, const float* __restrict__ pos,
                         u16* __restrict__ xp) {
  long e = ((long)blockIdx.x * blockDim.x + threadIdx.x) * 8;
  int d = (int)(e & (DMODEL - 1));
  long tok = e >> 10;
  int s = (int)(tok % SEQLEN);
  f32x4 a0 = *(const f32x4*)(x + e);
  f32x4 a1 = *(const f32x4*)(x + e + 4);
  f32x4 p0 = *(const f32x4*)(pos + (size_t)s * DMODEL + d);
  f32x4 p1 = *(const f32x4*)(pos + (size_t)s * DMODEL + d + 4);
  u16x8 o;
  o[0] = f2b(a0[0] + p0[0]); o[1] = f2b(a0[1] + p0[1]);
  o[2] = f2b(a0[2] + p0[2]); o[3] = f2b(a0[3] + p0[3]);
  o[4] = f2b(a1[0] + p1[0]); o[5] = f2b(a1[1] + p1[1]);
  o[6] = f2b(a1[2] + p1[2]); o[7] = f2b(a1[3] + p1[3]);
  *(u16x8*)(xp + e) = o;
}

// ---------------- prep: W2 = bf16 row-interleaved [Win;Wg] (row-major) ----------------
// W2 row r (r = 32j+k): k<16 -> Win[16j+k], else Wg[16j+k-16].
__global__ void k_prep_w(const float* __restrict__ Win, const float* __restrict__ Wg,
                         u16* __restrict__ w2) {
  long e = ((long)blockIdx.x * blockDim.x + threadIdx.x) * 8;  // < 4194304
  int r = (int)(e >> 10), c = (int)(e & 1023);
  int srow = ((r >> 5) << 4) + (r & 15);
  const float* src = ((r & 16) ? Wg : Win) + (size_t)srow * DMODEL + c;
  f32x4 a0 = *(const f32x4*)src;
  f32x4 a1 = *(const f32x4*)(src + 4);
  u16x8 o;
  o[0] = f2b(a0[0]); o[1] = f2b(a0[1]); o[2] = f2b(a0[2]); o[3] = f2b(a0[3]);
  o[4] = f2b(a1[0]); o[5] = f2b(a1[1]); o[6] = f2b(a1[2]); o[7] = f2b(a1[3]);
  *(u16x8*)(w2 + e) = o;
}

// ---------------- prep: W_B, W_C -> bf16 ----------------
__global__ void k_prep_wbc(const float* __restrict__ WB, const float* __restrict__ WC,
                           u16* __restrict__ wb, u16* __restrict__ wc) {
  long e = ((long)blockIdx.x * blockDim.x + threadIdx.x) * 8;  // < 49152
  const float* src; u16* dst;
  if (e < 32768) { src = WB + e; dst = wb + e; }
  else           { src = WC + (e - 32768); dst = wc + (e - 32768); }
  f32x4 a0 = *(const f32x4*)src;
  f32x4 a1 = *(const f32x4*)(src + 4);
  u16x8 o;
  o[0] = f2b(a0[0]); o[1] = f2b(a0[1]); o[2] = f2b(a0[2]); o[3] = f2b(a0[3]);
  o[4] = f2b(a1[0]); o[5] = f2b(a1[1]); o[6] = f2b(a1[2]); o[7] = f2b(a1[3]);
  *(u16x8*)(dst) = o;
}

// ============ fused dual GEMM: 256x256, BK=64, m201-style 4-phase/K-tile ============
// 512 threads = 8 waves (2M x 4N); per-wave C = 128x64 (acc[8][4]).
// LDS 128KB: 2 bufs x {A-k0,A-k1,B-k0,B-k1} 16KB each (256 rows x 32K, 64B rows).
// Phase (ks,nh): {ds_read frags, stage 1 half-tile (2 GLL), barrier, lgkm0, 16 MFMA, barrier}.
// Stage plan: P0->B-k1(t+1) [other buf]; P1->A-k0(t+2); P2->B-k0(t+2); P3->A-k1(t+2)
// (each target region's last read was the previous phase, barrier-separated -> WAR-safe).
// ONE vmcnt(6) per tile at tile start (2 GLL x 3 stages newer than the newest needed half).
__global__ __launch_bounds__(512, 2) void k_gemm256(
    const u16* __restrict__ XP, const u16* __restrict__ W2, const u16* __restrict__ WBb,
    const float* __restrict__ b_in, const float* __restrict__ b_gate,
    float* __restrict__ Bpart) {
  extern __shared__ __align__(16) u16 smem[];
  char* smemc = (char*)smem;

  const int tid = threadIdx.x;
  const int bid = blockIdx.x;
  // XCD-affine swizzle: XCD owns nb pairs {2x,2x+1} -> its 1MB of W2 stays L2-resident
  const int nb = ((bid & 7) << 1) | ((bid >> 3) & 1);  // 0..15
  const int rb = bid >> 4;                             // 0..199
  const int m0 = rb << 8;
  const int n0 = nb << 8;

  // --- staging: row = tid>>2 (0..127, +128 in 2nd GLL), chunk (tid&3) inverse-swizzled ---
  const int srow = tid >> 2;
  const int csrc = ((tid & 3) ^ ((tid >> 3) & 3)) << 3;      // ^ (row>>1)&3, verified R11
  const u16* gA = XP + (size_t)(m0 + srow) * DMODEL + csrc;
  const u16* gB = W2 + (size_t)(n0 + srow) * DMODEL + csrc;
  const int ldst = tid << 3;                                 // u16 offset (16B/thread)

  // --- wave/frag constants ---
  const int wid = tid >> 6, lane = tid & 63;
  const int wm = wid >> 2, wn = wid & 3;
  const int l15 = lane & 15, lhi = lane >> 4;
  const int kch = (lhi ^ ((l15 >> 1) & 3)) << 4;             // swizzled 16B chunk (byte)

  auto rdA = [&](int bufb, int ks, int m) -> s16x8 {         // rows 64B apart
    const int rr = (wm << 7) + (m << 4) + l15;
    return *(const s16x8*)(smemc + bufb + (ks << 14) + (rr << 6) + kch);
  };
  auto rdB = [&](int bufb, int ks, int n) -> s16x8 {
    const int rr = (wn << 6) + (n << 4) + l15;
    return *(const s16x8*)(smemc + bufb + 32768 + (ks << 14) + (rr << 6) + kch);
  };
  // stage half-tile: mat 0=A,1=B; kh 0/1; tile t. Region = 16KB = 2 GLL.
  auto STG = [&](int mat, int kh, int t) {
    const int bu = ((t & 1) << 15) + (mat << 14) + (kh << 13);   // u16 offset
    const u16* g = (mat ? gB : gA) + ((size_t)t << 6) + (kh << 5);
    GLL(g,          smem + bu + ldst);
    GLL(g + 131072, smem + bu + 4096 + ldst);                    // rows 128..255
  };

  f32x4 acc[8][4] = {};

  // prologue: tile 0 fully + A-k0/B-k0/A-k1 of tile 1 (B-k1(1) staged at t=0 P0)
  STG(0, 0, 0); STG(1, 0, 0); STG(0, 1, 0); STG(1, 1, 0);
  STG(0, 0, 1); STG(1, 0, 1); STG(0, 1, 1);

#pragma unroll 1
  for (int t = 0; t < 16; ++t) {
    if (t == 15) asm volatile("s_waitcnt vmcnt(0)" ::: "memory");
    else         asm volatile("s_waitcnt vmcnt(6)" ::: "memory");
    SB0();
    asm volatile("s_barrier" ::: "memory");
    SB0();
    const int bufb = (t & 1) << 16;
    s16x8 a0[8], a1[8], bl[2], bh[2];

    // ---- P0 (ks0, n-lo): read a0[8]+bl[2]; stage B-k1(t+1) ----
#pragma unroll
    for (int m = 0; m < 8; ++m) a0[m] = rdA(bufb, 0, m);
#pragma unroll
    for (int n = 0; n < 2; ++n) bl[n] = rdB(bufb, 0, n);
    if (t < 15) STG(1, 1, t + 1);
    SB0();
    asm volatile("s_barrier" ::: "memory");
    asm volatile("s_waitcnt lgkmcnt(0)" ::: "memory");
    SB0();
    __builtin_amdgcn_s_setprio(1);
#pragma unroll
    for (int m = 0; m < 8; ++m)
#pragma unroll
      for (int n = 0; n < 2; ++n)
        acc[m][n] = __builtin_amdgcn_mfma_f32_16x16x32_bf16(a0[m], bl[n], acc[m][n], 0, 0, 0);
    __builtin_amdgcn_s_setprio(0);
    SB0();
    asm volatile("s_barrier" ::: "memory");
    SB0();

    // ---- P1 (ks0, n-hi): read bh[2]; stage A-k0(t+2) ----
#pragma unroll
    for (int n = 0; n < 2; ++n) bh[n] = rdB(bufb, 0, n + 2);
    if (t < 14) STG(0, 0, t + 2);
    SB0();
    asm volatile("s_barrier" ::: "memory");
    asm volatile("s_waitcnt lgkmcnt(0)" ::: "memory");
    SB0();
    __builtin_amdgcn_s_setprio(1);
#pragma unroll
    for (int m = 0; m < 8; ++m)
#pragma unroll
      for (int n = 0; n < 2; ++n)
        acc[m][n + 2] = __builtin_amdgcn_mfma_f32_16x16x32_bf16(a0[m], bh[n], acc[m][n + 2], 0, 0, 0);
    __builtin_amdgcn_s_setprio(0);
    SB0();
    asm volatile("s_barrier" ::: "memory");
    SB0();

    // ---- P2 (ks1, n-lo): read a1[8]+bl[2]; stage B-k0(t+2) ----
#pragma unroll
    for (int m = 0; m < 8; ++m) a1[m] = rdA(bufb, 1, m);
#pragma unroll
    for (int n = 0; n < 2; ++n) bl[n] = rdB(bufb, 1, n);
    if (t < 14) STG(1, 0, t + 2);
    SB0();
    asm volatile("s_barrier" ::: "memory");
    asm volatile("s_waitcnt lgkmcnt(0)" ::: "memory");
    SB0();
    __builtin_amdgcn_s_setprio(1);
#pragma unroll
    for (int m = 0; m < 8; ++m)
#pragma unroll
      for (int n = 0; n < 2; ++n)
        acc[m][n] = __builtin_amdgcn_mfma_f32_16x16x32_bf16(a1[m], bl[n], acc[m][n], 0, 0, 0);
    __builtin_amdgcn_s_setprio(0);
    SB0();
    asm volatile("s_barrier" ::: "memory");
    SB0();

    // ---- P3 (ks1, n-hi): read bh[2]; stage A-k1(t+2) ----
#pragma unroll
    for (int n = 0; n < 2; ++n) bh[n] = rdB(bufb, 1, n + 2);
    if (t < 14) STG(0, 1, t + 2);
    SB0();
    asm volatile("s_barrier" ::: "memory");
    asm volatile("s_waitcnt lgkmcnt(0)" ::: "memory");
    SB0();
    __builtin_amdgcn_s_setprio(1);
#pragma unroll
    for (int m = 0; m < 8; ++m)
#pragma unroll
      for (int n = 0; n < 2; ++n)
        acc[m][n + 2] = __builtin_amdgcn_mfma_f32_16x16x32_bf16(a1[m], bh[n], acc[m][n + 2], 0, 0, 0);
    __builtin_amdgcn_s_setprio(0);
    SB0();
    asm volatile("s_barrier" ::: "memory");
    SB0();
  }

  // all phase reads drained per-phase; final barrier before epilogue overwrites LDS
  asm volatile("s_waitcnt lgkmcnt(0)" ::: "memory");
  SB0();
  asm volatile("s_barrier" ::: "memory");
  SB0();

  // --- epilogue: in-register gating (acc[m][2u]=proj, acc[m][2u+1]=gate) ---
  u16* xg = smem;  // [256][136] bf16 (+8 pad), 69632 B
  float bi[2], bg[2];
#pragma unroll
  for (int u = 0; u < 2; ++u) {
    const int gcol = (nb << 7) + (((wn << 1) + u) << 4) + l15;
    bi[u] = b_in[gcol];
    bg[u] = b_gate[gcol];
  }
#pragma unroll
  for (int m = 0; m < 8; ++m)
#pragma unroll
    for (int u = 0; u < 2; ++u)
#pragma unroll
      for (int j = 0; j < 4; ++j) {
        const int row = (wm << 7) + (m << 4) + (lhi << 2) + j;
        const int col = (((wn << 1) + u) << 4) + l15;
        float pv = acc[m][2 * u][j] + bi[u];
        float gv = acc[m][2 * u + 1][j] + bg[u];
        xg[row * 136 + col] = f2b(pv / (1.0f + __expf(-gv)));
      }
  asm volatile("s_waitcnt lgkmcnt(0)" ::: "memory");
  asm volatile("s_barrier" ::: "memory");

  // --- mini-GEMM: Bpart[nb][m0+row][state] = xg @ W_B[:, nb*128..+128]^T ---
  f32x4 bacc[2] = {};
#pragma unroll
  for (int m2 = 0; m2 < 2; ++m2)
#pragma unroll
    for (int kc = 0; kc < 4; ++kc) {
      s16x8 av = *(const s16x8*)(xg + ((wid << 5) + (m2 << 4) + l15) * 136 + (kc << 5) + (lhi << 3));
      s16x8 bv = *(const s16x8*)(WBb + (size_t)l15 * DINNER + (nb << 7) + (kc << 5) + (lhi << 3));
      bacc[m2] = __builtin_amdgcn_mfma_f32_16x16x32_bf16(av, bv, bacc[m2], 0, 0, 0);
    }
#pragma unroll
  for (int m2 = 0; m2 < 2; ++m2) {
    float* outp = Bpart + ((size_t)nb * TOKENS + m0 + (wid << 5) + (m2 << 4) + (lhi << 2)) * NSTATE + l15;
#pragma unroll
    for (int j = 0; j < 4; ++j) outp[j * NSTATE] = bacc[m2][j];
  }
}

// ---------------- C = XP @ W_C^T + b_C (MFMA; W_C staged once in LDS) ----------------
__global__ __launch_bounds__(256) void k_C(const u16* __restrict__ XP, const u16* __restrict__ WC,
                                           const float* __restrict__ bC, float* __restrict__ Cb) {
  __shared__ __align__(16) u16 wcl[16 * 1032];  // rows padded +8 elems
  const int tid = threadIdx.x;
  const int m0 = blockIdx.x << 6;
#pragma unroll
  for (int i = 0; i < 8; ++i) {
    int c = i * 256 + tid;                       // 16B chunk id, 0..2047
    int row = c >> 7, col = c & 127;
    *(u16x8*)(wcl + row * 1032 + (col << 3)) = *(const u16x8*)(WC + (row << 10) + (col << 3));
  }
  __syncthreads();
  const int wv = tid >> 6, lane = tid & 63;
  const int l15 = lane & 15, lhi = lane >> 4;
  const u16* xr = XP + (size_t)(m0 + (wv << 4) + l15) * DMODEL + (lhi << 3);
  const u16* wr = wcl + l15 * 1032 + (lhi << 3);
  f32x4 acc = {};
#pragma unroll
  for (int t = 0; t < 32; ++t) {
    s16x8 av = *(const s16x8*)(xr + t * 32);
    s16x8 bv = *(const s16x8*)(wr + t * 32);
    acc = __builtin_amdgcn_mfma_f32_16x16x32_bf16(av, bv, acc, 0, 0, 0);
  }
  const float bc = bC[l15];
  float* o = Cb + (size_t)(m0 + (wv << 4) + (lhi << 2)) * NSTATE + l15;
#pragma unroll
  for (int j = 0; j < 4; ++j) o[j * NSTATE] = acc[j] + bc;
}

// ---------------- B = sum_chunks Bpart + b_B ----------------
__global__ void k_finB(const float* __restrict__ Bpart, const float* __restrict__ bB,
                       float* __restrict__ Bf) {
  const long i = (long)blockIdx.x * blockDim.x + threadIdx.x;  // per float4
  f32x4 s = {};
#pragma unroll
  for (int cb = 0; cb < 16; ++cb)
    s += *(const f32x4*)(Bpart + (size_t)cb * (TOKENS * NSTATE) + i * 4);
  s += *(const f32x4*)(bB + ((i & 3) << 2));
  *(f32x4*)(Bf + i * 4) = s;
}

// ---------------- sequential scan: h = A*h + B; y = h*C ----------------
__global__ void k_scan(const float* __restrict__ Bf, const float* __restrict__ Cb,
                       const float* __restrict__ Alog, float* __restrict__ Y) {
  const int t = threadIdx.x;
  const int b = blockIdx.x * 16 + (t >> 4);
  const int n = t & 15;
  const float A = __expf(0.01f * __expf(Alog[n]));
  float h = 0.f;
  const size_t base = (size_t)b * SEQLEN * NSTATE + n;
  for (int s = 0; s < SEQLEN; ++s) {
    const size_t idx = base + (size_t)s * NSTATE;
    h = A * h + Bf[idx];
    Y[idx] = h * Cb[idx];
  }
}

// ---------------- out = Y @ W_out[:, :16]^T + b_out ----------------
__global__ __launch_bounds__(256) void k_out(const float* __restrict__ Y,
                                             const float* __restrict__ Wout,
                                             const float* __restrict__ bout,
                                             float* __restrict__ out) {
  __shared__ float ys[32][16];
  const int tid = threadIdx.x;
  const long t0 = (long)blockIdx.x * 32;
  for (int i = tid; i < 512; i += 256) ys[i >> 4][i & 15] = Y[t0 * 16 + i];
  const int d0 = tid << 2;
  float w[4][16];
#pragma unroll
  for (int j = 0; j < 4; ++j)
#pragma unroll
    for (int q = 0; q < 4; ++q) {
      f32x4 wv = *(const f32x4*)(Wout + (size_t)(d0 + j) * DINNER + q * 4);
#pragma unroll
      for (int e = 0; e < 4; ++e) w[j][q * 4 + e] = wv[e];
    }
  f32x4 bo = *(const f32x4*)(bout + d0);
  __syncthreads();
  for (int r = 0; r < 32; ++r) {
    f32x4 acc = bo;
#pragma unroll
    for (int n = 0; n < 16; ++n) {
      const float yv = ys[r][n];
      acc[0] += yv * w[0][n];
      acc[1] += yv * w[1][n];
      acc[2] += yv * w[2][n];
      acc[3] += yv * w[3][n];
    }
    *(f32x4*)(out + (t0 + r) * 1024 + d0) = acc;
  }
}

extern "C" void kernel_launch(void* const* d_in, const int* in_sizes, int n_in,
                              void* d_out, int out_size, void* d_ws, size_t ws_size,
                              hipStream_t stream) {
  const float* x    = (const float*)d_in[0];
  const float* pos  = (const float*)d_in[1];
  const float* Win  = (const float*)d_in[2];
  const float* bin  = (const float*)d_in[3];
  const float* Wg   = (const float*)d_in[4];
  const float* bg   = (const float*)d_in[5];
  const float* Alog = (const float*)d_in[6];
  const float* WB   = (const float*)d_in[7];
  const float* bB   = (const float*)d_in[8];
  const float* WC   = (const float*)d_in[9];
  const float* bC   = (const float*)d_in[10];
  const float* Wout = (const float*)d_in[11];
  const float* bout = (const float*)d_in[12];

  char* ws = (char*)d_ws;
  u16*   XP   = (u16*)(ws + OFF_XP);
  u16*   W2   = (u16*)(ws + OFF_WCAT);
  u16*   WBb  = (u16*)(ws + OFF_WB);
  u16*   WCb  = (u16*)(ws + OFF_WC);
  float* BP   = (float*)(ws + OFF_BPART);
  float* BF   = (float*)(ws + OFF_BFIN);
  float* CB   = (float*)(ws + OFF_CBUF);
  float* Yb   = (float*)(ws + OFF_Y);

  hipFuncSetAttribute((const void*)k_gemm256,
                      hipFuncAttributeMaxDynamicSharedMemorySize, 131072);

  k_prep_x  <<<25600, 256, 0, stream>>>(x, pos, XP);
  k_prep_w  <<<2048, 256, 0, stream>>>(Win, Wg, W2);
  k_prep_wbc<<<24, 256, 0, stream>>>(WB, WC, WBb, WCb);
  k_gemm256 <<<3200, 512, 131072, stream>>>(XP, W2, WBb, bin, bg, BP);
  k_C       <<<800, 256, 0, stream>>>(XP, WCb, bC, CB);
  k_finB    <<<800, 256, 0, stream>>>(BP, bB, BF);
  k_scan    <<<32, 256, 0, stream>>>(BF, CB, Alog, Yb);
  k_out     <<<1600, 256, 0, stream>>>(Yb, Wout, bout, (float*)d_out);
}

// Round 13
// 601.361 us; speedup vs baseline: 5.1322x; 1.0073x over previous
//
#include <hip/hip_runtime.h>
#include <hip/hip_bf16.h>
#include <stdint.h>

typedef unsigned short u16;
typedef u16   u16x8 __attribute__((ext_vector_type(8)));
typedef short s16x8 __attribute__((ext_vector_type(8)));
typedef float f32x4 __attribute__((ext_vector_type(4)));

#define TOKENS 51200
#define DMODEL 1024
#define DINNER 2048
#define NSTATE 16
#define SEQLEN 100

// workspace layout (bytes)
#define OFF_XP    0ull          // 51200*1024*2   = 104857600
#define OFF_WCAT  104857600ull  // W2: 4096*1024*2 = 8388608
#define OFF_WB    113246208ull  // 16*2048*2      =     65536
#define OFF_WC    113311744ull  // 16*1024*2      =     32768
#define OFF_BPART 113344512ull  // 16*51200*16*4  =  52428800
#define OFF_BFIN  165773312ull  // 51200*16*4     =   3276800
#define OFF_CBUF  169050112ull  // 51200*16*4
#define OFF_Y     172326912ull  // 51200*16*4     -> total 175603712 bytes

__device__ __forceinline__ u16 f2b(float f) {  // f32 -> bf16 RNE
  uint32_t u = __float_as_uint(f);
  uint32_t r = (u + 0x7fffu + ((u >> 16) & 1u)) >> 16;
  return (u16)r;
}
__device__ __forceinline__ float b2f(u16 u) {
  return __uint_as_float(((uint32_t)u) << 16);
}

#define GLL(gp, lp) __builtin_amdgcn_global_load_lds( \
    (__attribute__((address_space(1))) unsigned int*)(gp), \
    (__attribute__((address_space(3))) unsigned int*)(lp), 16, 0, 0)
#define SB0() __builtin_amdgcn_sched_barrier(0)

// ---------------- prep: XP = bf16(x + pos_emb) ----------------
__global__ void k_prep_x(const float* __restrict__ x, const float* __restrict__ pos,
                         u16* __restrict__ xp) {
  long e = ((long)blockIdx.x * blockDim.x + threadIdx.x) * 8;
  int d = (int)(e & (DMODEL - 1));
  long tok = e >> 10;
  int s = (int)(tok % SEQLEN);
  f32x4 a0 = *(const f32x4*)(x + e);
  f32x4 a1 = *(const f32x4*)(x + e + 4);
  f32x4 p0 = *(const f32x4*)(pos + (size_t)s * DMODEL + d);
  f32x4 p1 = *(const f32x4*)(pos + (size_t)s * DMODEL + d + 4);
  u16x8 o;
  o[0] = f2b(a0[0] + p0[0]); o[1] = f2b(a0[1] + p0[1]);
  o[2] = f2b(a0[2] + p0[2]); o[3] = f2b(a0[3] + p0[3]);
  o[4] = f2b(a1[0] + p1[0]); o[5] = f2b(a1[1] + p1[1]);
  o[6] = f2b(a1[2] + p1[2]); o[7] = f2b(a1[3] + p1[3]);
  *(u16x8*)(xp + e) = o;
}

// ---------------- prep: W2 = bf16 row-interleaved [Win;Wg] (row-major) ----------------
// W2 row r (r = 32j+k): k<16 -> Win[16j+k], else Wg[16j+k-16].
__global__ void k_prep_w(const float* __restrict__ Win, const float* __restrict__ Wg,
                         u16* __restrict__ w2) {
  long e = ((long)blockIdx.x * blockDim.x + threadIdx.x) * 8;  // < 4194304
  int r = (int)(e >> 10), c = (int)(e & 1023);
  int srow = ((r >> 5) << 4) + (r & 15);
  const float* src = ((r & 16) ? Wg : Win) + (size_t)srow * DMODEL + c;
  f32x4 a0 = *(const f32x4*)src;
  f32x4 a1 = *(const f32x4*)(src + 4);
  u16x8 o;
  o[0] = f2b(a0[0]); o[1] = f2b(a0[1]); o[2] = f2b(a0[2]); o[3] = f2b(a0[3]);
  o[4] = f2b(a1[0]); o[5] = f2b(a1[1]); o[6] = f2b(a1[2]); o[7] = f2b(a1[3]);
  *(u16x8*)(w2 + e) = o;
}

// ---------------- prep: W_B, W_C -> bf16 ----------------
__global__ void k_prep_wbc(const float* __restrict__ WB, const float* __restrict__ WC,
                           u16* __restrict__ wb, u16* __restrict__ wc) {
  long e = ((long)blockIdx.x * blockDim.x + threadIdx.x) * 8;  // < 49152
  const float* src; u16* dst;
  if (e < 32768) { src = WB + e; dst = wb + e; }
  else           { src = WC + (e - 32768); dst = wc + (e - 32768); }
  f32x4 a0 = *(const f32x4*)src;
  f32x4 a1 = *(const f32x4*)(src + 4);
  u16x8 o;
  o[0] = f2b(a0[0]); o[1] = f2b(a0[1]); o[2] = f2b(a0[2]); o[3] = f2b(a0[3]);
  o[4] = f2b(a1[0]); o[5] = f2b(a1[1]); o[6] = f2b(a1[2]); o[7] = f2b(a1[3]);
  *(u16x8*)(dst) = o;
}

// ====== fused dual GEMM: 256x256 tile, 1024 threads (16 waves, 4M x 4N), BK=32 ======
// Per wave C = 64x64 -> acc[4][4] = 64 AGPR; ~120 regs/wave -> 4 waves/SIMD (R11-proven).
// LDS: 4-slot ring x 32KB {A 16KB, B 16KB}; depth-3 prefetch; 2 GLL/tile (16KB statements).
// Per K-tile: lgkm0; vmcnt(4 counted, tail 2/0); barrier; 8 ds_read; stage T(t+3); 16 MFMA.
// Byte economy of 256^2 tile (3.2GB total staged) x double occupancy (4 waves/SIMD).
__global__ __launch_bounds__(1024, 4) void k_gemm256(
    const u16* __restrict__ XP, const u16* __restrict__ W2, const u16* __restrict__ WBb,
    const float* __restrict__ b_in, const float* __restrict__ b_gate,
    float* __restrict__ Bpart) {
  extern __shared__ __align__(16) u16 smem[];
  char* smemc = (char*)smem;

  const int tid = threadIdx.x;
  const int bid = blockIdx.x;
  // XCD-affine: XCD owns nb pairs {2x,2x+1} -> its 1MB of W2 stays L2-resident
  const int nb = ((bid & 7) << 1) | ((bid >> 3) & 1);  // 0..15
  const int rb = bid >> 4;                             // 0..199
  const int m0 = rb << 8;
  const int n0 = nb << 8;

  // --- staging: row = tid>>2 (0..255), chunk (tid&3) inverse-swizzled: ^=(row>>1)&3 ---
  const int srow = tid >> 2;
  const int csrc = ((tid & 3) ^ ((tid >> 3) & 3)) << 3;  // element offset in row
  const u16* gA = XP + (size_t)(m0 + srow) * DMODEL + csrc;
  const u16* gB = W2 + (size_t)(n0 + srow) * DMODEL + csrc;
  const int ldst = tid << 3;                             // u16 offset (16B/thread)

  // --- wave/frag constants: 16 waves = 4M x 4N, per-wave 64x64 ---
  const int wid = tid >> 6, lane = tid & 63;
  const int wm = wid >> 2, wn = wid & 3;
  const int l15 = lane & 15, lhi = lane >> 4;
  const int kch = (lhi ^ ((l15 >> 1) & 3)) << 4;         // swizzled 16B chunk (byte)

  auto rdA = [&](int slotb, int m) -> s16x8 {            // rows 64B apart
    return *(const s16x8*)(smemc + slotb + (((wm << 6) + (m << 4) + l15) << 6) + kch);
  };
  auto rdB = [&](int slotb, int n) -> s16x8 {
    return *(const s16x8*)(smemc + slotb + 16384 + (((wn << 6) + (n << 4) + l15) << 6) + kch);
  };
  // stage tile t into slot t&3: A (256 rows x 64B) 1 GLL + B 1 GLL
  auto STG = [&](int t) {
    u16* d = smem + ((t & 3) << 14) + ldst;              // slot stride 16384 u16 = 32KB
    const u16* a_ = gA + ((size_t)t << 5);
    const u16* b_ = gB + ((size_t)t << 5);
    GLL(a_, d);
    GLL(b_, d + 8192);
  };

  f32x4 acc[4][4] = {};

  // prologue: tiles 0,1,2 (FIFO: A0,B0,A1,B1,A2,B2 = 6 GLL/wave)
  STG(0); STG(1); STG(2);

#pragma unroll 1
  for (int t = 0; t < 32; ++t) {
    asm volatile("s_waitcnt lgkmcnt(0)" ::: "memory");   // drain own reads of slot (t-1)&3
    if (t < 30)       asm volatile("s_waitcnt vmcnt(4)" ::: "memory");  // tile t resident
    else if (t == 30) asm volatile("s_waitcnt vmcnt(2)" ::: "memory");
    else              asm volatile("s_waitcnt vmcnt(0)" ::: "memory");
    SB0();
    asm volatile("s_barrier" ::: "memory");
    SB0();
    const int slotb = (t & 3) << 15;                     // byte offset

    s16x8 a[4], b[4];
#pragma unroll
    for (int m = 0; m < 4; ++m) a[m] = rdA(slotb, m);
#pragma unroll
    for (int n = 0; n < 4; ++n) b[n] = rdB(slotb, n);
    if (t < 29) STG(t + 3);                              // slot (t+3)&3 == (t-1)&3: drained
    SB0();

    __builtin_amdgcn_s_setprio(1);
#pragma unroll
    for (int m = 0; m < 4; ++m)
#pragma unroll
      for (int n = 0; n < 4; ++n)
        acc[m][n] = __builtin_amdgcn_mfma_f32_16x16x32_bf16(a[m], b[n], acc[m][n], 0, 0, 0);
    __builtin_amdgcn_s_setprio(0);
  }

  // all reads done before epilogue overwrites LDS
  asm volatile("s_waitcnt lgkmcnt(0)" ::: "memory");
  SB0();
  asm volatile("s_barrier" ::: "memory");
  SB0();

  // --- epilogue: in-register gating (acc[m][2u]=proj, acc[m][2u+1]=gate) ---
  u16* xg = smem;  // [256][136] bf16 (+8 pad), 69632 B
  float bi[2], bg[2];
#pragma unroll
  for (int u = 0; u < 2; ++u) {
    const int gcol = (nb << 7) + (wn << 5) + (u << 4) + l15;  // true channel index
    bi[u] = b_in[gcol];
    bg[u] = b_gate[gcol];
  }
#pragma unroll
  for (int m = 0; m < 4; ++m)
#pragma unroll
    for (int u = 0; u < 2; ++u)
#pragma unroll
      for (int j = 0; j < 4; ++j) {
        const int row = (wm << 6) + (m << 4) + (lhi << 2) + j;
        const int col = (wn << 5) + (u << 4) + l15;           // gated col 0..127
        float pv = acc[m][2 * u][j] + bi[u];
        float gv = acc[m][2 * u + 1][j] + bg[u];
        xg[row * 136 + col] = f2b(pv / (1.0f + __expf(-gv)));
      }
  asm volatile("s_waitcnt lgkmcnt(0)" ::: "memory");
  asm volatile("s_barrier" ::: "memory");

  // --- mini-GEMM: Bpart[nb][m0+row][state] = xg @ W_B[:, nb*128..+128]^T ---
  // 16 waves x 16 rows = 256 rows; 4 MFMAs per wave over K=128
  f32x4 bacc = {};
#pragma unroll
  for (int kc = 0; kc < 4; ++kc) {
    s16x8 av = *(const s16x8*)(xg + ((wid << 4) + l15) * 136 + (kc << 5) + (lhi << 3));
    s16x8 bv = *(const s16x8*)(WBb + (size_t)l15 * DINNER + (nb << 7) + (kc << 5) + (lhi << 3));
    bacc = __builtin_amdgcn_mfma_f32_16x16x32_bf16(av, bv, bacc, 0, 0, 0);
  }
  float* outp = Bpart + ((size_t)nb * TOKENS + m0 + (wid << 4) + (lhi << 2)) * NSTATE + l15;
#pragma unroll
  for (int j = 0; j < 4; ++j) outp[j * NSTATE] = bacc[j];
}

// ---------------- C = XP @ W_C^T + b_C (MFMA; W_C staged once in LDS) ----------------
__global__ __launch_bounds__(256) void k_C(const u16* __restrict__ XP, const u16* __restrict__ WC,
                                           const float* __restrict__ bC, float* __restrict__ Cb) {
  __shared__ __align__(16) u16 wcl[16 * 1032];  // rows padded +8 elems
  const int tid = threadIdx.x;
  const int m0 = blockIdx.x << 6;
#pragma unroll
  for (int i = 0; i < 8; ++i) {
    int c = i * 256 + tid;                       // 16B chunk id, 0..2047
    int row = c >> 7, col = c & 127;
    *(u16x8*)(wcl + row * 1032 + (col << 3)) = *(const u16x8*)(WC + (row << 10) + (col << 3));
  }
  __syncthreads();
  const int wv = tid >> 6, lane = tid & 63;
  const int l15 = lane & 15, lhi = lane >> 4;
  const u16* xr = XP + (size_t)(m0 + (wv << 4) + l15) * DMODEL + (lhi << 3);
  const u16* wr = wcl + l15 * 1032 + (lhi << 3);
  f32x4 acc = {};
#pragma unroll
  for (int t = 0; t < 32; ++t) {
    s16x8 av = *(const s16x8*)(xr + t * 32);
    s16x8 bv = *(const s16x8*)(wr + t * 32);
    acc = __builtin_amdgcn_mfma_f32_16x16x32_bf16(av, bv, acc, 0, 0, 0);
  }
  const float bc = bC[l15];
  float* o = Cb + (size_t)(m0 + (wv << 4) + (lhi << 2)) * NSTATE + l15;
#pragma unroll
  for (int j = 0; j < 4; ++j) o[j * NSTATE] = acc[j] + bc;
}

// ---------------- B = sum_chunks Bpart + b_B ----------------
__global__ void k_finB(const float* __restrict__ Bpart, const float* __restrict__ bB,
                       float* __restrict__ Bf) {
  const long i = (long)blockIdx.x * blockDim.x + threadIdx.x;  // per float4
  f32x4 s = {};
#pragma unroll
  for (int cb = 0; cb < 16; ++cb)
    s += *(const f32x4*)(Bpart + (size_t)cb * (TOKENS * NSTATE) + i * 4);
  s += *(const f32x4*)(bB + ((i & 3) << 2));
  *(f32x4*)(Bf + i * 4) = s;
}

// ---------------- sequential scan: h = A*h + B; y = h*C ----------------
__global__ void k_scan(const float* __restrict__ Bf, const float* __restrict__ Cb,
                       const float* __restrict__ Alog, float* __restrict__ Y) {
  const int t = threadIdx.x;
  const int b = blockIdx.x * 16 + (t >> 4);
  const int n = t & 15;
  const float A = __expf(0.01f * __expf(Alog[n]));
  float h = 0.f;
  const size_t base = (size_t)b * SEQLEN * NSTATE + n;
  for (int s = 0; s < SEQLEN; ++s) {
    const size_t idx = base + (size_t)s * NSTATE;
    h = A * h + Bf[idx];
    Y[idx] = h * Cb[idx];
  }
}

// ---------------- out = Y @ W_out[:, :16]^T + b_out ----------------
__global__ __launch_bounds__(256) void k_out(const float* __restrict__ Y,
                                             const float* __restrict__ Wout,
                                             const float* __restrict__ bout,
                                             float* __restrict__ out) {
  __shared__ float ys[32][16];
  const int tid = threadIdx.x;
  const long t0 = (long)blockIdx.x * 32;
  for (int i = tid; i < 512; i += 256) ys[i >> 4][i & 15] = Y[t0 * 16 + i];
  const int d0 = tid << 2;
  float w[4][16];
#pragma unroll
  for (int j = 0; j < 4; ++j)
#pragma unroll
    for (int q = 0; q < 4; ++q) {
      f32x4 wv = *(const f32x4*)(Wout + (size_t)(d0 + j) * DINNER + q * 4);
#pragma unroll
      for (int e = 0; e < 4; ++e) w[j][q * 4 + e] = wv[e];
    }
  f32x4 bo = *(const f32x4*)(bout + d0);
  __syncthreads();
  for (int r = 0; r < 32; ++r) {
    f32x4 acc = bo;
#pragma unroll
    for (int n = 0; n < 16; ++n) {
      const float yv = ys[r][n];
      acc[0] += yv * w[0][n];
      acc[1] += yv * w[1][n];
      acc[2] += yv * w[2][n];
      acc[3] += yv * w[3][n];
    }
    *(f32x4*)(out + (t0 + r) * 1024 + d0) = acc;
  }
}

extern "C" void kernel_launch(void* const* d_in, const int* in_sizes, int n_in,
                              void* d_out, int out_size, void* d_ws, size_t ws_size,
                              hipStream_t stream) {
  const float* x    = (const float*)d_in[0];
  const float* pos  = (const float*)d_in[1];
  const float* Win  = (const float*)d_in[2];
  const float* bin  = (const float*)d_in[3];
  const float* Wg   = (const float*)d_in[4];
  const float* bg   = (const float*)d_in[5];
  const float* Alog = (const float*)d_in[6];
  const float* WB   = (const float*)d_in[7];
  const float* bB   = (const float*)d_in[8];
  const float* WC   = (const float*)d_in[9];
  const float* bC   = (const float*)d_in[10];
  const float* Wout = (const float*)d_in[11];
  const float* bout = (const float*)d_in[12];

  char* ws = (char*)d_ws;
  u16*   XP   = (u16*)(ws + OFF_XP);
  u16*   W2   = (u16*)(ws + OFF_WCAT);
  u16*   WBb  = (u16*)(ws + OFF_WB);
  u16*   WCb  = (u16*)(ws + OFF_WC);
  float* BP   = (float*)(ws + OFF_BPART);
  float* BF   = (float*)(ws + OFF_BFIN);
  float* CB   = (float*)(ws + OFF_CBUF);
  float* Yb   = (float*)(ws + OFF_Y);

  hipFuncSetAttribute((const void*)k_gemm256,
                      hipFuncAttributeMaxDynamicSharedMemorySize, 131072);

  k_prep_x  <<<25600, 256, 0, stream>>>(x, pos, XP);
  k_prep_w  <<<2048, 256, 0, stream>>>(Win, Wg, W2);
  k_prep_wbc<<<24, 256, 0, stream>>>(WB, WC, WBb, WCb);
  k_gemm256 <<<3200, 1024, 131072, stream>>>(XP, W2, WBb, bin, bg, BP);
  k_C       <<<800, 256, 0, stream>>>(XP, WCb, bC, CB);
  k_finB    <<<800, 256, 0, stream>>>(BP, bB, BF);
  k_scan    <<<32, 256, 0, stream>>>(BF, CB, Alog, Yb);
  k_out     <<<1600, 256, 0, stream>>>(Yb, Wout, bout, (float*)d_out);
}

// Round 14
// 588.479 us; speedup vs baseline: 5.2446x; 1.0219x over previous
//
#include <hip/hip_runtime.h>
#include <hip/hip_bf16.h>
#include <stdint.h>

typedef unsigned short u16;
typedef u16   u16x8 __attribute__((ext_vector_type(8)));
typedef short s16x8 __attribute__((ext_vector_type(8)));
typedef float f32x4 __attribute__((ext_vector_type(4)));

#define TOKENS 51200
#define DMODEL 1024
#define DINNER 2048
#define NSTATE 16
#define SEQLEN 100

// workspace layout (bytes)
#define OFF_XP    0ull          // 51200*1024*2   = 104857600
#define OFF_WCAT  104857600ull  // W2: 4096*1024*2 = 8388608
#define OFF_WB    113246208ull  // 16*2048*2      =     65536
#define OFF_WC    113311744ull  // (unused now)
#define OFF_BPART 113344512ull  // 16*51200*16*4  =  52428800
#define OFF_BFIN  165773312ull  // 51200*16*4     =   3276800
#define OFF_CBUF  169050112ull  // 51200*16*4
#define OFF_Y     172326912ull  // 51200*16*4     -> total 175603712 bytes

__device__ __forceinline__ u16 f2b(float f) {  // f32 -> bf16 RNE
  uint32_t u = __float_as_uint(f);
  uint32_t r = (u + 0x7fffu + ((u >> 16) & 1u)) >> 16;
  return (u16)r;
}
__device__ __forceinline__ float b2f(u16 u) {
  return __uint_as_float(((uint32_t)u) << 16);
}

#define GLL(gp, lp) __builtin_amdgcn_global_load_lds( \
    (__attribute__((address_space(1))) unsigned int*)(gp), \
    (__attribute__((address_space(3))) unsigned int*)(lp), 16, 0, 0)
#define SB0() __builtin_amdgcn_sched_barrier(0)

// ---------------- prep: W2 = bf16 row-interleaved [Win;Wg] (row-major) ----------------
// W2 row r (r = 32j+k): k<16 -> Win[16j+k], else Wg[16j+k-16].
__global__ void k_prep_w(const float* __restrict__ Win, const float* __restrict__ Wg,
                         u16* __restrict__ w2) {
  long e = ((long)blockIdx.x * blockDim.x + threadIdx.x) * 8;  // < 4194304
  int r = (int)(e >> 10), c = (int)(e & 1023);
  int srow = ((r >> 5) << 4) + (r & 15);
  const float* src = ((r & 16) ? Wg : Win) + (size_t)srow * DMODEL + c;
  f32x4 a0 = *(const f32x4*)src;
  f32x4 a1 = *(const f32x4*)(src + 4);
  u16x8 o;
  o[0] = f2b(a0[0]); o[1] = f2b(a0[1]); o[2] = f2b(a0[2]); o[3] = f2b(a0[3]);
  o[4] = f2b(a1[0]); o[5] = f2b(a1[1]); o[6] = f2b(a1[2]); o[7] = f2b(a1[3]);
  *(u16x8*)(w2 + e) = o;
}

// ---------------- prep: W_B -> bf16 ----------------
__global__ void k_prep_wb(const float* __restrict__ WB, u16* __restrict__ wb) {
  long e = ((long)blockIdx.x * blockDim.x + threadIdx.x) * 8;  // < 32768
  f32x4 a0 = *(const f32x4*)(WB + e);
  f32x4 a1 = *(const f32x4*)(WB + e + 4);
  u16x8 o;
  o[0] = f2b(a0[0]); o[1] = f2b(a0[1]); o[2] = f2b(a0[2]); o[3] = f2b(a0[3]);
  o[4] = f2b(a1[0]); o[5] = f2b(a1[1]); o[6] = f2b(a1[2]); o[7] = f2b(a1[3]);
  *(u16x8*)(wb + e) = o;
}

// ======== fused: XP = bf16(x+pos)  AND  C = XP @ W_C^T + b_C (MFMA) ========
// 800 blocks x 256 threads (4 waves x 16 rows). W_C (f32) converted+staged in LDS once.
// Per t in 0..31: read x,pos (32B/lane, coalesced per 4-lane group), convert -> write XP
// (16B/lane, 64B/row contiguous) -> MFMA frag against W_C.
__global__ __launch_bounds__(256) void k_prepx_C(
    const float* __restrict__ x, const float* __restrict__ pos,
    const float* __restrict__ WC, const float* __restrict__ bC,
    u16* __restrict__ xp, float* __restrict__ Cb) {
  __shared__ __align__(16) u16 wcl[16 * 1032];  // rows padded +8 elems
  const int tid = threadIdx.x;
  const int m0 = blockIdx.x << 6;
#pragma unroll
  for (int i = 0; i < 8; ++i) {
    int c = i * 256 + tid;                       // 8-elem chunk id, 0..2047
    int row = c >> 7, col8 = (c & 127) << 3;
    f32x4 a0 = *(const f32x4*)(WC + (row << 10) + col8);
    f32x4 a1 = *(const f32x4*)(WC + (row << 10) + col8 + 4);
    u16x8 o;
    o[0] = f2b(a0[0]); o[1] = f2b(a0[1]); o[2] = f2b(a0[2]); o[3] = f2b(a0[3]);
    o[4] = f2b(a1[0]); o[5] = f2b(a1[1]); o[6] = f2b(a1[2]); o[7] = f2b(a1[3]);
    *(u16x8*)(wcl + row * 1032 + col8) = o;
  }
  __syncthreads();
  const int wv = tid >> 6, lane = tid & 63;
  const int l15 = lane & 15, lhi = lane >> 4;
  const int row = m0 + (wv << 4) + l15;
  const int s = row % SEQLEN;
  const float* xr = x + (size_t)row * DMODEL + (lhi << 3);
  const float* pr = pos + (size_t)s * DMODEL + (lhi << 3);
  u16* xw = xp + (size_t)row * DMODEL + (lhi << 3);
  const u16* wr = wcl + l15 * 1032 + (lhi << 3);
  f32x4 acc = {};
#pragma unroll 4
  for (int t = 0; t < 32; ++t) {
    f32x4 x0 = *(const f32x4*)(xr + t * 32);
    f32x4 x1 = *(const f32x4*)(xr + t * 32 + 4);
    f32x4 p0 = *(const f32x4*)(pr + t * 32);
    f32x4 p1 = *(const f32x4*)(pr + t * 32 + 4);
    u16x8 v;
    v[0] = f2b(x0[0] + p0[0]); v[1] = f2b(x0[1] + p0[1]);
    v[2] = f2b(x0[2] + p0[2]); v[3] = f2b(x0[3] + p0[3]);
    v[4] = f2b(x1[0] + p1[0]); v[5] = f2b(x1[1] + p1[1]);
    v[6] = f2b(x1[2] + p1[2]); v[7] = f2b(x1[3] + p1[3]);
    *(u16x8*)(xw + t * 32) = v;
    s16x8 av; 
#pragma unroll
    for (int j = 0; j < 8; ++j) av[j] = (short)v[j];
    s16x8 bv = *(const s16x8*)(wr + t * 32);
    acc = __builtin_amdgcn_mfma_f32_16x16x32_bf16(av, bv, acc, 0, 0, 0);
  }
  const float bc = bC[l15];
  float* o = Cb + (size_t)(m0 + (wv << 4) + (lhi << 2)) * NSTATE + l15;
#pragma unroll
  for (int j = 0; j < 4; ++j) o[j * NSTATE] = acc[j] + bc;
}

// ============ fused dual GEMM (R7-verified: skeleton + interleaved issue) ============
// 256x256 tile, BK=64, 512 threads = 8 waves (2M x 4N), per-wave C = 128x64 (acc[8][4]).
// LDS 128KB: 2 bufs x {A 32KB, B 32KB}. Depth-2 staging; vmcnt(8) counted at tile start.
__global__ __launch_bounds__(512, 2) void k_gemm256(
    const u16* __restrict__ XP, const u16* __restrict__ W2, const u16* __restrict__ WBb,
    const float* __restrict__ b_in, const float* __restrict__ b_gate,
    float* __restrict__ Bpart) {
  extern __shared__ __align__(16) u16 smem[];
  char* smemc = (char*)smem;

  const int tid = threadIdx.x;
  const int bid = blockIdx.x;
  // XCD-affine swizzle: XCD owns nb pairs {2x,2x+1} -> its 1MB of W2 stays L2-resident
  const int nb = ((bid & 7) << 1) | ((bid >> 3) & 1);  // 0..15
  const int rb = bid >> 4;                             // 0..199
  const int m0 = rb << 8;
  const int n0 = nb << 8;

  // --- staging addresses: row tid>>3, chunk (tid&7) inverse-swizzled ---
  const int arow  = tid >> 3;                              // 0..63
  const int acolsw = ((tid & 7) ^ (arow & 7)) << 3;
  const u16* gA = XP + (size_t)(m0 + arow) * DMODEL + acolsw;
  const u16* gB = W2 + (size_t)(n0 + arow) * DMODEL + acolsw;
  const int ldst = tid << 3;                               // u16 offset (16B/thread)

  // --- wave/frag constants ---
  const int wid = tid >> 6, lane = tid & 63;
  const int wm = wid >> 2, wn = wid & 3;
  const int l15 = lane & 15, lhi = lane >> 4;
  const int swz = (l15 & 7) << 4;
  const int arow0 = (wm << 7) + l15;
  const int brow0 = (wn << 6) + l15;

  auto rdA = [&](int bufb, int m, int ks) -> s16x8 {
    return *(const s16x8*)(smemc + bufb + ((arow0 + (m << 4)) << 7) +
                           (((ks << 6) + (lhi << 4)) ^ swz));
  };
  auto rdB = [&](int bufb, int n, int ks) -> s16x8 {
    return *(const s16x8*)(smemc + bufb + 32768 + ((brow0 + (n << 4)) << 7) +
                           (((ks << 6) + (lhi << 4)) ^ swz));
  };
  auto stgA = [&](int t, int i) {
    const int bb = (t & 1) << 15;
    const size_t go = (size_t)t << 6;
    GLL(gA + go + ((size_t)(2 * i)     << 16), smem + bb + ((2 * i)     << 12) + ldst);
    GLL(gA + go + ((size_t)(2 * i + 1) << 16), smem + bb + ((2 * i + 1) << 12) + ldst);
  };
  auto stgB = [&](int t, int i) {
    const int bb = (t & 1) << 15;
    const size_t go = (size_t)t << 6;
    GLL(gB + go + ((size_t)(2 * i)     << 16), smem + bb + 16384 + ((2 * i)     << 12) + ldst);
    GLL(gB + go + ((size_t)(2 * i + 1) << 16), smem + bb + 16384 + ((2 * i + 1) << 12) + ldst);
  };

  f32x4 acc[8][4] = {};

  // prologue: stage tiles 0 and 1 (FIFO: A(0)x4,B(0)x4,A(1)x4,B(1)x4)
  stgA(0, 0); stgA(0, 1); stgB(0, 0); stgB(0, 1);
  stgA(1, 0); stgA(1, 1); stgB(1, 0); stgB(1, 1);

#pragma unroll 1
  for (int t = 0; t < 16; ++t) {
    if (t == 15) asm volatile("s_waitcnt vmcnt(0)" ::: "memory");
    else         asm volatile("s_waitcnt vmcnt(8)" ::: "memory");
    SB0();
    asm volatile("s_barrier" ::: "memory");
    SB0();
    const int bufb = (t & 1) << 16;

    s16x8 afl[4][2], afh[4][2], bfr[4][2];
    // ---- cluster 1: A-lo frags + B n0-1; 16 MFMA ----
#pragma unroll
    for (int m = 0; m < 4; ++m) { afl[m][0] = rdA(bufb, m, 0); afl[m][1] = rdA(bufb, m, 1); }
#pragma unroll
    for (int n = 0; n < 2; ++n) { bfr[n][0] = rdB(bufb, n, 0); bfr[n][1] = rdB(bufb, n, 1); }
    __builtin_amdgcn_s_setprio(1);
#pragma unroll
    for (int ks = 0; ks < 2; ++ks)
#pragma unroll
      for (int m = 0; m < 4; ++m)
#pragma unroll
        for (int n = 0; n < 2; ++n)
          acc[m][n] = __builtin_amdgcn_mfma_f32_16x16x32_bf16(afl[m][ks], bfr[n][ks], acc[m][n], 0, 0, 0);
    __builtin_amdgcn_s_setprio(0);

    // ---- cluster 2: B n2-3; 16 MFMA ----
#pragma unroll
    for (int n = 2; n < 4; ++n) { bfr[n][0] = rdB(bufb, n, 0); bfr[n][1] = rdB(bufb, n, 1); }
    __builtin_amdgcn_s_setprio(1);
#pragma unroll
    for (int ks = 0; ks < 2; ++ks)
#pragma unroll
      for (int m = 0; m < 4; ++m)
#pragma unroll
        for (int n = 0; n < 2; ++n)
          acc[m][n + 2] = __builtin_amdgcn_mfma_f32_16x16x32_bf16(afl[m][ks], bfr[n + 2][ks], acc[m][n + 2], 0, 0, 0);
    __builtin_amdgcn_s_setprio(0);

    // ---- A-hi frags; mid-tile buffer-free proof ----
#pragma unroll
    for (int m = 0; m < 4; ++m) { afh[m][0] = rdA(bufb, m + 4, 0); afh[m][1] = rdA(bufb, m + 4, 1); }
    asm volatile("s_waitcnt lgkmcnt(0)" ::: "memory");
    SB0();
    asm volatile("s_barrier" ::: "memory");
    SB0();

    // ---- post-mid: 3 MFMA clusters (16/8/8) with 4 staging slots between ----
    if (t < 14) stgA(t + 2, 0);
    SB0();
    __builtin_amdgcn_s_setprio(1);
#pragma unroll
    for (int ks = 0; ks < 2; ++ks)
#pragma unroll
      for (int m = 0; m < 4; ++m)
#pragma unroll
        for (int n = 0; n < 2; ++n)
          acc[m + 4][n + 2] = __builtin_amdgcn_mfma_f32_16x16x32_bf16(afh[m][ks], bfr[n + 2][ks], acc[m + 4][n + 2], 0, 0, 0);
    __builtin_amdgcn_s_setprio(0);
    SB0();
    if (t < 14) stgA(t + 2, 1);
    SB0();
    __builtin_amdgcn_s_setprio(1);
#pragma unroll
    for (int m = 0; m < 4; ++m)
#pragma unroll
      for (int n = 0; n < 2; ++n)
        acc[m + 4][n] = __builtin_amdgcn_mfma_f32_16x16x32_bf16(afh[m][0], bfr[n][0], acc[m + 4][n], 0, 0, 0);
    __builtin_amdgcn_s_setprio(0);
    SB0();
    if (t < 14) stgB(t + 2, 0);
    SB0();
    __builtin_amdgcn_s_setprio(1);
#pragma unroll
    for (int m = 0; m < 4; ++m)
#pragma unroll
      for (int n = 0; n < 2; ++n)
        acc[m + 4][n] = __builtin_amdgcn_mfma_f32_16x16x32_bf16(afh[m][1], bfr[n][1], acc[m + 4][n], 0, 0, 0);
    __builtin_amdgcn_s_setprio(0);
    SB0();
    if (t < 14) stgB(t + 2, 1);
    SB0();
  }

  // close the loop: all waves done reading buf1 before epilogue overwrites LDS
  asm volatile("s_waitcnt lgkmcnt(0)" ::: "memory");
  SB0();
  asm volatile("s_barrier" ::: "memory");
  SB0();

  // --- epilogue: in-register gating (acc[m][2u]=proj, acc[m][2u+1]=gate) ---
  u16* xg = smem;  // [256][136] bf16 (+8 pad), 69632 B
  float bi[2], bg[2];
#pragma unroll
  for (int u = 0; u < 2; ++u) {
    const int gcol = (nb << 7) + (((wn << 1) + u) << 4) + l15;
    bi[u] = b_in[gcol];
    bg[u] = b_gate[gcol];
  }
#pragma unroll
  for (int m = 0; m < 8; ++m)
#pragma unroll
    for (int u = 0; u < 2; ++u)
#pragma unroll
      for (int j = 0; j < 4; ++j) {
        const int row = (wm << 7) + (m << 4) + (lhi << 2) + j;
        const int col = (((wn << 1) + u) << 4) + l15;
        float pv = acc[m][2 * u][j] + bi[u];
        float gv = acc[m][2 * u + 1][j] + bg[u];
        xg[row * 136 + col] = f2b(pv / (1.0f + __expf(-gv)));
      }
  asm volatile("s_waitcnt lgkmcnt(0)" ::: "memory");
  asm volatile("s_barrier" ::: "memory");

  // --- mini-GEMM: Bpart[nb][m0+row][state] = xg @ W_B[:, nb*128..+128]^T ---
  f32x4 bacc[2] = {};
#pragma unroll
  for (int m2 = 0; m2 < 2; ++m2)
#pragma unroll
    for (int kc = 0; kc < 4; ++kc) {
      s16x8 av = *(const s16x8*)(xg + ((wid << 5) + (m2 << 4) + l15) * 136 + (kc << 5) + (lhi << 3));
      s16x8 bv = *(const s16x8*)(WBb + (size_t)l15 * DINNER + (nb << 7) + (kc << 5) + (lhi << 3));
      bacc[m2] = __builtin_amdgcn_mfma_f32_16x16x32_bf16(av, bv, bacc[m2], 0, 0, 0);
    }
#pragma unroll
  for (int m2 = 0; m2 < 2; ++m2) {
    float* outp = Bpart + ((size_t)nb * TOKENS + m0 + (wid << 5) + (m2 << 4) + (lhi << 2)) * NSTATE + l15;
#pragma unroll
    for (int j = 0; j < 4; ++j) outp[j * NSTATE] = bacc[m2][j];
  }
}

// ---------------- B = sum_chunks Bpart + b_B ----------------
__global__ void k_finB(const float* __restrict__ Bpart, const float* __restrict__ bB,
                       float* __restrict__ Bf) {
  const long i = (long)blockIdx.x * blockDim.x + threadIdx.x;  // per float4
  f32x4 s = {};
#pragma unroll
  for (int cb = 0; cb < 16; ++cb)
    s += *(const f32x4*)(Bpart + (size_t)cb * (TOKENS * NSTATE) + i * 4);
  s += *(const f32x4*)(bB + ((i & 3) << 2));
  *(f32x4*)(Bf + i * 4) = s;
}

// ---------------- sequential scan (software-pipelined): h = A*h + B; y = h*C ----------------
// One thread per (batch, state). Loads batched 10-deep: the h-chain is the only serial dep,
// so 20 independent loads per chunk hide latency (vs 1 dependent load-wait per step before).
__global__ __launch_bounds__(128) void k_scan(const float* __restrict__ Bf, const float* __restrict__ Cb,
                                              const float* __restrict__ Alog, float* __restrict__ Y) {
  const int t = threadIdx.x;
  const int b = blockIdx.x * 8 + (t >> 4);
  const int n = t & 15;
  const float A = __expf(0.01f * __expf(Alog[n]));
  float h = 0.f;
  const size_t base = (size_t)b * SEQLEN * NSTATE + n;
  float Bv[10], Cv[10];
#pragma unroll 1
  for (int c = 0; c < 10; ++c) {
    const size_t cb = base + (size_t)c * 10 * NSTATE;
#pragma unroll
    for (int s = 0; s < 10; ++s) { Bv[s] = Bf[cb + s * NSTATE]; Cv[s] = Cb[cb + s * NSTATE]; }
#pragma unroll
    for (int s = 0; s < 10; ++s) { h = A * h + Bv[s]; Y[cb + s * NSTATE] = h * Cv[s]; }
  }
}

// ---------------- out = Y @ W_out[:, :16]^T + b_out ----------------
__global__ __launch_bounds__(256) void k_out(const float* __restrict__ Y,
                                             const float* __restrict__ Wout,
                                             const float* __restrict__ bout,
                                             float* __restrict__ out) {
  __shared__ float ys[32][16];
  const int tid = threadIdx.x;
  const long t0 = (long)blockIdx.x * 32;
  for (int i = tid; i < 512; i += 256) ys[i >> 4][i & 15] = Y[t0 * 16 + i];
  const int d0 = tid << 2;
  float w[4][16];
#pragma unroll
  for (int j = 0; j < 4; ++j)
#pragma unroll
    for (int q = 0; q < 4; ++q) {
      f32x4 wv = *(const f32x4*)(Wout + (size_t)(d0 + j) * DINNER + q * 4);
#pragma unroll
      for (int e = 0; e < 4; ++e) w[j][q * 4 + e] = wv[e];
    }
  f32x4 bo = *(const f32x4*)(bout + d0);
  __syncthreads();
  for (int r = 0; r < 32; ++r) {
    f32x4 acc = bo;
#pragma unroll
    for (int n = 0; n < 16; ++n) {
      const float yv = ys[r][n];
      acc[0] += yv * w[0][n];
      acc[1] += yv * w[1][n];
      acc[2] += yv * w[2][n];
      acc[3] += yv * w[3][n];
    }
    *(f32x4*)(out + (t0 + r) * 1024 + d0) = acc;
  }
}

extern "C" void kernel_launch(void* const* d_in, const int* in_sizes, int n_in,
                              void* d_out, int out_size, void* d_ws, size_t ws_size,
                              hipStream_t stream) {
  const float* x    = (const float*)d_in[0];
  const float* pos  = (const float*)d_in[1];
  const float* Win  = (const float*)d_in[2];
  const float* bin  = (const float*)d_in[3];
  const float* Wg   = (const float*)d_in[4];
  const float* bg   = (const float*)d_in[5];
  const float* Alog = (const float*)d_in[6];
  const float* WB   = (const float*)d_in[7];
  const float* bB   = (const float*)d_in[8];
  const float* WC   = (const float*)d_in[9];
  const float* bC   = (const float*)d_in[10];
  const float* Wout = (const float*)d_in[11];
  const float* bout = (const float*)d_in[12];

  char* ws = (char*)d_ws;
  u16*   XP   = (u16*)(ws + OFF_XP);
  u16*   W2   = (u16*)(ws + OFF_WCAT);
  u16*   WBb  = (u16*)(ws + OFF_WB);
  float* BP   = (float*)(ws + OFF_BPART);
  float* BF   = (float*)(ws + OFF_BFIN);
  float* CB   = (float*)(ws + OFF_CBUF);
  float* Yb   = (float*)(ws + OFF_Y);

  hipFuncSetAttribute((const void*)k_gemm256,
                      hipFuncAttributeMaxDynamicSharedMemorySize, 131072);

  k_prep_w  <<<2048, 256, 0, stream>>>(Win, Wg, W2);
  k_prep_wb <<<16, 256, 0, stream>>>(WB, WBb);
  k_prepx_C <<<800, 256, 0, stream>>>(x, pos, WC, bC, XP, CB);
  k_gemm256 <<<3200, 512, 131072, stream>>>(XP, W2, WBb, bin, bg, BP);
  k_finB    <<<800, 256, 0, stream>>>(BP, bB, BF);
  k_scan    <<<64, 128, 0, stream>>>(BF, CB, Alog, Yb);
  k_out     <<<1600, 256, 0, stream>>>(Yb, Wout, bout, (float*)d_out);
}

// Round 15
// 562.840 us; speedup vs baseline: 5.4835x; 1.0456x over previous
//
#include <hip/hip_runtime.h>
#include <hip/hip_bf16.h>
#include <stdint.h>

typedef unsigned short u16;
typedef u16   u16x8 __attribute__((ext_vector_type(8)));
typedef short s16x8 __attribute__((ext_vector_type(8)));
typedef float f32x4 __attribute__((ext_vector_type(4)));

#define TOKENS 51200
#define DMODEL 1024
#define DINNER 2048
#define NSTATE 16
#define SEQLEN 100

// workspace layout (bytes)
#define OFF_XP    0ull          // 51200*1024*2   = 104857600
#define OFF_WCAT  104857600ull  // W2: 4096*1024*2 = 8388608
#define OFF_WB    113246208ull  // 16*2048*2      =     65536
#define OFF_WC    113311744ull  // 16*1024*2      =     32768
#define OFF_BPART 113344512ull  // 16*51200*16*4  =  52428800
#define OFF_BFIN  165773312ull  // 51200*16*4     =   3276800
#define OFF_CBUF  169050112ull  // 51200*16*4
#define OFF_Y     172326912ull  // 51200*16*4     -> total 175603712 bytes

__device__ __forceinline__ u16 f2b(float f) {  // f32 -> bf16 RNE
  uint32_t u = __float_as_uint(f);
  uint32_t r = (u + 0x7fffu + ((u >> 16) & 1u)) >> 16;
  return (u16)r;
}
__device__ __forceinline__ float b2f(u16 u) {
  return __uint_as_float(((uint32_t)u) << 16);
}

#define GLL(gp, lp) __builtin_amdgcn_global_load_lds( \
    (__attribute__((address_space(1))) unsigned int*)(gp), \
    (__attribute__((address_space(3))) unsigned int*)(lp), 16, 0, 0)
#define SB0() __builtin_amdgcn_sched_barrier(0)

// ---------------- prep: XP = bf16(x + pos_emb) ----------------
__global__ void k_prep_x(const float* __restrict__ x, const float* __restrict__ pos,
                         u16* __restrict__ xp) {
  long e = ((long)blockIdx.x * blockDim.x + threadIdx.x) * 8;
  int d = (int)(e & (DMODEL - 1));
  long tok = e >> 10;
  int s = (int)(tok % SEQLEN);
  f32x4 a0 = *(const f32x4*)(x + e);
  f32x4 a1 = *(const f32x4*)(x + e + 4);
  f32x4 p0 = *(const f32x4*)(pos + (size_t)s * DMODEL + d);
  f32x4 p1 = *(const f32x4*)(pos + (size_t)s * DMODEL + d + 4);
  u16x8 o;
  o[0] = f2b(a0[0] + p0[0]); o[1] = f2b(a0[1] + p0[1]);
  o[2] = f2b(a0[2] + p0[2]); o[3] = f2b(a0[3] + p0[3]);
  o[4] = f2b(a1[0] + p1[0]); o[5] = f2b(a1[1] + p1[1]);
  o[6] = f2b(a1[2] + p1[2]); o[7] = f2b(a1[3] + p1[3]);
  *(u16x8*)(xp + e) = o;
}

// ---------------- prep: W2 = bf16 row-interleaved [Win;Wg] (row-major) ----------------
// W2 row r (r = 32j+k): k<16 -> Win[16j+k], else Wg[16j+k-16].
__global__ void k_prep_w(const float* __restrict__ Win, const float* __restrict__ Wg,
                         u16* __restrict__ w2) {
  long e = ((long)blockIdx.x * blockDim.x + threadIdx.x) * 8;  // < 4194304
  int r = (int)(e >> 10), c = (int)(e & 1023);
  int srow = ((r >> 5) << 4) + (r & 15);
  const float* src = ((r & 16) ? Wg : Win) + (size_t)srow * DMODEL + c;
  f32x4 a0 = *(const f32x4*)src;
  f32x4 a1 = *(const f32x4*)(src + 4);
  u16x8 o;
  o[0] = f2b(a0[0]); o[1] = f2b(a0[1]); o[2] = f2b(a0[2]); o[3] = f2b(a0[3]);
  o[4] = f2b(a1[0]); o[5] = f2b(a1[1]); o[6] = f2b(a1[2]); o[7] = f2b(a1[3]);
  *(u16x8*)(w2 + e) = o;
}

// ---------------- prep: W_B, W_C -> bf16 ----------------
__global__ void k_prep_wbc(const float* __restrict__ WB, const float* __restrict__ WC,
                           u16* __restrict__ wb, u16* __restrict__ wc) {
  long e = ((long)blockIdx.x * blockDim.x + threadIdx.x) * 8;  // < 49152
  const float* src; u16* dst;
  if (e < 32768) { src = WB + e; dst = wb + e; }
  else           { src = WC + (e - 32768); dst = wc + (e - 32768); }
  f32x4 a0 = *(const f32x4*)src;
  f32x4 a1 = *(const f32x4*)(src + 4);
  u16x8 o;
  o[0] = f2b(a0[0]); o[1] = f2b(a0[1]); o[2] = f2b(a0[2]); o[3] = f2b(a0[3]);
  o[4] = f2b(a1[0]); o[5] = f2b(a1[1]); o[6] = f2b(a1[2]); o[7] = f2b(a1[3]);
  *(u16x8*)(dst) = o;
}

// ============ fused dual GEMM (R7-verified: skeleton + interleaved issue) ============
// 256x256 tile, BK=64, 512 threads = 8 waves (2M x 4N), per-wave C = 128x64 (acc[8][4]).
// LDS 128KB: 2 bufs x {A 32KB, B 32KB}. Depth-2 staging; vmcnt(8) counted at tile start.
__global__ __launch_bounds__(512, 2) void k_gemm256(
    const u16* __restrict__ XP, const u16* __restrict__ W2, const u16* __restrict__ WBb,
    const float* __restrict__ b_in, const float* __restrict__ b_gate,
    float* __restrict__ Bpart) {
  extern __shared__ __align__(16) u16 smem[];
  char* smemc = (char*)smem;

  const int tid = threadIdx.x;
  const int bid = blockIdx.x;
  // XCD-affine swizzle: XCD owns nb pairs {2x,2x+1} -> its 1MB of W2 stays L2-resident
  const int nb = ((bid & 7) << 1) | ((bid >> 3) & 1);  // 0..15
  const int rb = bid >> 4;                             // 0..199
  const int m0 = rb << 8;
  const int n0 = nb << 8;

  // --- staging addresses: row tid>>3, chunk (tid&7) inverse-swizzled ---
  const int arow  = tid >> 3;                              // 0..63
  const int acolsw = ((tid & 7) ^ (arow & 7)) << 3;
  const u16* gA = XP + (size_t)(m0 + arow) * DMODEL + acolsw;
  const u16* gB = W2 + (size_t)(n0 + arow) * DMODEL + acolsw;
  const int ldst = tid << 3;                               // u16 offset (16B/thread)

  // --- wave/frag constants ---
  const int wid = tid >> 6, lane = tid & 63;
  const int wm = wid >> 2, wn = wid & 3;
  const int l15 = lane & 15, lhi = lane >> 4;
  const int swz = (l15 & 7) << 4;
  const int arow0 = (wm << 7) + l15;
  const int brow0 = (wn << 6) + l15;

  auto rdA = [&](int bufb, int m, int ks) -> s16x8 {
    return *(const s16x8*)(smemc + bufb + ((arow0 + (m << 4)) << 7) +
                           (((ks << 6) + (lhi << 4)) ^ swz));
  };
  auto rdB = [&](int bufb, int n, int ks) -> s16x8 {
    return *(const s16x8*)(smemc + bufb + 32768 + ((brow0 + (n << 4)) << 7) +
                           (((ks << 6) + (lhi << 4)) ^ swz));
  };
  auto stgA = [&](int t, int i) {
    const int bb = (t & 1) << 15;
    const size_t go = (size_t)t << 6;
    GLL(gA + go + ((size_t)(2 * i)     << 16), smem + bb + ((2 * i)     << 12) + ldst);
    GLL(gA + go + ((size_t)(2 * i + 1) << 16), smem + bb + ((2 * i + 1) << 12) + ldst);
  };
  auto stgB = [&](int t, int i) {
    const int bb = (t & 1) << 15;
    const size_t go = (size_t)t << 6;
    GLL(gB + go + ((size_t)(2 * i)     << 16), smem + bb + 16384 + ((2 * i)     << 12) + ldst);
    GLL(gB + go + ((size_t)(2 * i + 1) << 16), smem + bb + 16384 + ((2 * i + 1) << 12) + ldst);
  };

  f32x4 acc[8][4] = {};

  // prologue: stage tiles 0 and 1 (FIFO: A(0)x4,B(0)x4,A(1)x4,B(1)x4)
  stgA(0, 0); stgA(0, 1); stgB(0, 0); stgB(0, 1);
  stgA(1, 0); stgA(1, 1); stgB(1, 0); stgB(1, 1);

#pragma unroll 1
  for (int t = 0; t < 16; ++t) {
    if (t == 15) asm volatile("s_waitcnt vmcnt(0)" ::: "memory");
    else         asm volatile("s_waitcnt vmcnt(8)" ::: "memory");
    SB0();
    asm volatile("s_barrier" ::: "memory");
    SB0();
    const int bufb = (t & 1) << 16;

    s16x8 afl[4][2], afh[4][2], bfr[4][2];
    // ---- cluster 1: A-lo frags + B n0-1; 16 MFMA ----
#pragma unroll
    for (int m = 0; m < 4; ++m) { afl[m][0] = rdA(bufb, m, 0); afl[m][1] = rdA(bufb, m, 1); }
#pragma unroll
    for (int n = 0; n < 2; ++n) { bfr[n][0] = rdB(bufb, n, 0); bfr[n][1] = rdB(bufb, n, 1); }
    __builtin_amdgcn_s_setprio(1);
#pragma unroll
    for (int ks = 0; ks < 2; ++ks)
#pragma unroll
      for (int m = 0; m < 4; ++m)
#pragma unroll
        for (int n = 0; n < 2; ++n)
          acc[m][n] = __builtin_amdgcn_mfma_f32_16x16x32_bf16(afl[m][ks], bfr[n][ks], acc[m][n], 0, 0, 0);
    __builtin_amdgcn_s_setprio(0);

    // ---- cluster 2: B n2-3; 16 MFMA ----
#pragma unroll
    for (int n = 2; n < 4; ++n) { bfr[n][0] = rdB(bufb, n, 0); bfr[n][1] = rdB(bufb, n, 1); }
    __builtin_amdgcn_s_setprio(1);
#pragma unroll
    for (int ks = 0; ks < 2; ++ks)
#pragma unroll
      for (int m = 0; m < 4; ++m)
#pragma unroll
        for (int n = 0; n < 2; ++n)
          acc[m][n + 2] = __builtin_amdgcn_mfma_f32_16x16x32_bf16(afl[m][ks], bfr[n + 2][ks], acc[m][n + 2], 0, 0, 0);
    __builtin_amdgcn_s_setprio(0);

    // ---- A-hi frags; mid-tile buffer-free proof ----
#pragma unroll
    for (int m = 0; m < 4; ++m) { afh[m][0] = rdA(bufb, m + 4, 0); afh[m][1] = rdA(bufb, m + 4, 1); }
    asm volatile("s_waitcnt lgkmcnt(0)" ::: "memory");
    SB0();
    asm volatile("s_barrier" ::: "memory");
    SB0();

    // ---- post-mid: 3 MFMA clusters (16/8/8) with 4 staging slots between ----
    if (t < 14) stgA(t + 2, 0);
    SB0();
    __builtin_amdgcn_s_setprio(1);
#pragma unroll
    for (int ks = 0; ks < 2; ++ks)
#pragma unroll
      for (int m = 0; m < 4; ++m)
#pragma unroll
        for (int n = 0; n < 2; ++n)
          acc[m + 4][n + 2] = __builtin_amdgcn_mfma_f32_16x16x32_bf16(afh[m][ks], bfr[n + 2][ks], acc[m + 4][n + 2], 0, 0, 0);
    __builtin_amdgcn_s_setprio(0);
    SB0();
    if (t < 14) stgA(t + 2, 1);
    SB0();
    __builtin_amdgcn_s_setprio(1);
#pragma unroll
    for (int m = 0; m < 4; ++m)
#pragma unroll
      for (int n = 0; n < 2; ++n)
        acc[m + 4][n] = __builtin_amdgcn_mfma_f32_16x16x32_bf16(afh[m][0], bfr[n][0], acc[m + 4][n], 0, 0, 0);
    __builtin_amdgcn_s_setprio(0);
    SB0();
    if (t < 14) stgB(t + 2, 0);
    SB0();
    __builtin_amdgcn_s_setprio(1);
#pragma unroll
    for (int m = 0; m < 4; ++m)
#pragma unroll
      for (int n = 0; n < 2; ++n)
        acc[m + 4][n] = __builtin_amdgcn_mfma_f32_16x16x32_bf16(afh[m][1], bfr[n][1], acc[m + 4][n], 0, 0, 0);
    __builtin_amdgcn_s_setprio(0);
    SB0();
    if (t < 14) stgB(t + 2, 1);
    SB0();
  }

  // close the loop: all waves done reading buf1 before epilogue overwrites LDS
  asm volatile("s_waitcnt lgkmcnt(0)" ::: "memory");
  SB0();
  asm volatile("s_barrier" ::: "memory");
  SB0();

  // --- epilogue: in-register gating (acc[m][2u]=proj, acc[m][2u+1]=gate) ---
  u16* xg = smem;  // [256][136] bf16 (+8 pad), 69632 B
  float bi[2], bg[2];
#pragma unroll
  for (int u = 0; u < 2; ++u) {
    const int gcol = (nb << 7) + (((wn << 1) + u) << 4) + l15;
    bi[u] = b_in[gcol];
    bg[u] = b_gate[gcol];
  }
#pragma unroll
  for (int m = 0; m < 8; ++m)
#pragma unroll
    for (int u = 0; u < 2; ++u)
#pragma unroll
      for (int j = 0; j < 4; ++j) {
        const int row = (wm << 7) + (m << 4) + (lhi << 2) + j;
        const int col = (((wn << 1) + u) << 4) + l15;
        float pv = acc[m][2 * u][j] + bi[u];
        float gv = acc[m][2 * u + 1][j] + bg[u];
        xg[row * 136 + col] = f2b(pv / (1.0f + __expf(-gv)));
      }
  asm volatile("s_waitcnt lgkmcnt(0)" ::: "memory");
  asm volatile("s_barrier" ::: "memory");

  // --- mini-GEMM: Bpart[nb][m0+row][state] = xg @ W_B[:, nb*128..+128]^T ---
  f32x4 bacc[2] = {};
#pragma unroll
  for (int m2 = 0; m2 < 2; ++m2)
#pragma unroll
    for (int kc = 0; kc < 4; ++kc) {
      s16x8 av = *(const s16x8*)(xg + ((wid << 5) + (m2 << 4) + l15) * 136 + (kc << 5) + (lhi << 3));
      s16x8 bv = *(const s16x8*)(WBb + (size_t)l15 * DINNER + (nb << 7) + (kc << 5) + (lhi << 3));
      bacc[m2] = __builtin_amdgcn_mfma_f32_16x16x32_bf16(av, bv, bacc[m2], 0, 0, 0);
    }
#pragma unroll
  for (int m2 = 0; m2 < 2; ++m2) {
    float* outp = Bpart + ((size_t)nb * TOKENS + m0 + (wid << 5) + (m2 << 4) + (lhi << 2)) * NSTATE + l15;
#pragma unroll
    for (int j = 0; j < 4; ++j) outp[j * NSTATE] = bacc[m2][j];
  }
}

// ---------------- C = XP @ W_C^T + b_C (MFMA; W_C staged once in LDS) ----------------
__global__ __launch_bounds__(256) void k_C(const u16* __restrict__ XP, const u16* __restrict__ WC,
                                           const float* __restrict__ bC, float* __restrict__ Cb) {
  __shared__ __align__(16) u16 wcl[16 * 1032];  // rows padded +8 elems
  const int tid = threadIdx.x;
  const int m0 = blockIdx.x << 6;
#pragma unroll
  for (int i = 0; i < 8; ++i) {
    int c = i * 256 + tid;                       // 16B chunk id, 0..2047
    int row = c >> 7, col = c & 127;
    *(u16x8*)(wcl + row * 1032 + (col << 3)) = *(const u16x8*)(WC + (row << 10) + (col << 3));
  }
  __syncthreads();
  const int wv = tid >> 6, lane = tid & 63;
  const int l15 = lane & 15, lhi = lane >> 4;
  const u16* xr = XP + (size_t)(m0 + (wv << 4) + l15) * DMODEL + (lhi << 3);
  const u16* wr = wcl + l15 * 1032 + (lhi << 3);
  f32x4 acc = {};
#pragma unroll
  for (int t = 0; t < 32; ++t) {
    s16x8 av = *(const s16x8*)(xr + t * 32);
    s16x8 bv = *(const s16x8*)(wr + t * 32);
    acc = __builtin_amdgcn_mfma_f32_16x16x32_bf16(av, bv, acc, 0, 0, 0);
  }
  const float bc = bC[l15];
  float* o = Cb + (size_t)(m0 + (wv << 4) + (lhi << 2)) * NSTATE + l15;
#pragma unroll
  for (int j = 0; j < 4; ++j) o[j * NSTATE] = acc[j] + bc;
}

// ---------------- B = sum_chunks Bpart + b_B ----------------
__global__ void k_finB(const float* __restrict__ Bpart, const float* __restrict__ bB,
                       float* __restrict__ Bf) {
  const long i = (long)blockIdx.x * blockDim.x + threadIdx.x;  // per float4
  f32x4 s = {};
#pragma unroll
  for (int cb = 0; cb < 16; ++cb)
    s += *(const f32x4*)(Bpart + (size_t)cb * (TOKENS * NSTATE) + i * 4);
  s += *(const f32x4*)(bB + ((i & 3) << 2));
  *(f32x4*)(Bf + i * 4) = s;
}

// ---------------- sequential scan (software-pipelined): h = A*h + B; y = h*C ----------------
// One thread per (batch, state). Loads batched 10-deep: the h-chain is the only serial dep,
// so 20 independent loads per chunk hide latency (vs 1 dependent load-wait per step).
__global__ __launch_bounds__(128) void k_scan(const float* __restrict__ Bf, const float* __restrict__ Cb,
                                              const float* __restrict__ Alog, float* __restrict__ Y) {
  const int t = threadIdx.x;
  const int b = blockIdx.x * 8 + (t >> 4);
  const int n = t & 15;
  const float A = __expf(0.01f * __expf(Alog[n]));
  float h = 0.f;
  const size_t base = (size_t)b * SEQLEN * NSTATE + n;
  float Bv[10], Cv[10];
#pragma unroll 1
  for (int c = 0; c < 10; ++c) {
    const size_t cb = base + (size_t)c * 10 * NSTATE;
#pragma unroll
    for (int s = 0; s < 10; ++s) { Bv[s] = Bf[cb + s * NSTATE]; Cv[s] = Cb[cb + s * NSTATE]; }
#pragma unroll
    for (int s = 0; s < 10; ++s) { h = A * h + Bv[s]; Y[cb + s * NSTATE] = h * Cv[s]; }
  }
}

// ---------------- out = Y @ W_out[:, :16]^T + b_out ----------------
__global__ __launch_bounds__(256) void k_out(const float* __restrict__ Y,
                                             const float* __restrict__ Wout,
                                             const float* __restrict__ bout,
                                             float* __restrict__ out) {
  __shared__ float ys[32][16];
  const int tid = threadIdx.x;
  const long t0 = (long)blockIdx.x * 32;
  for (int i = tid; i < 512; i += 256) ys[i >> 4][i & 15] = Y[t0 * 16 + i];
  const int d0 = tid << 2;
  float w[4][16];
#pragma unroll
  for (int j = 0; j < 4; ++j)
#pragma unroll
    for (int q = 0; q < 4; ++q) {
      f32x4 wv = *(const f32x4*)(Wout + (size_t)(d0 + j) * DINNER + q * 4);
#pragma unroll
      for (int e = 0; e < 4; ++e) w[j][q * 4 + e] = wv[e];
    }
  f32x4 bo = *(const f32x4*)(bout + d0);
  __syncthreads();
  for (int r = 0; r < 32; ++r) {
    f32x4 acc = bo;
#pragma unroll
    for (int n = 0; n < 16; ++n) {
      const float yv = ys[r][n];
      acc[0] += yv * w[0][n];
      acc[1] += yv * w[1][n];
      acc[2] += yv * w[2][n];
      acc[3] += yv * w[3][n];
    }
    *(f32x4*)(out + (t0 + r) * 1024 + d0) = acc;
  }
}

extern "C" void kernel_launch(void* const* d_in, const int* in_sizes, int n_in,
                              void* d_out, int out_size, void* d_ws, size_t ws_size,
                              hipStream_t stream) {
  const float* x    = (const float*)d_in[0];
  const float* pos  = (const float*)d_in[1];
  const float* Win  = (const float*)d_in[2];
  const float* bin  = (const float*)d_in[3];
  const float* Wg   = (const float*)d_in[4];
  const float* bg   = (const float*)d_in[5];
  const float* Alog = (const float*)d_in[6];
  const float* WB   = (const float*)d_in[7];
  const float* bB   = (const float*)d_in[8];
  const float* WC   = (const float*)d_in[9];
  const float* bC   = (const float*)d_in[10];
  const float* Wout = (const float*)d_in[11];
  const float* bout = (const float*)d_in[12];

  char* ws = (char*)d_ws;
  u16*   XP   = (u16*)(ws + OFF_XP);
  u16*   W2   = (u16*)(ws + OFF_WCAT);
  u16*   WBb  = (u16*)(ws + OFF_WB);
  u16*   WCb  = (u16*)(ws + OFF_WC);
  float* BP   = (float*)(ws + OFF_BPART);
  float* BF   = (float*)(ws + OFF_BFIN);
  float* CB   = (float*)(ws + OFF_CBUF);
  float* Yb   = (float*)(ws + OFF_Y);

  hipFuncSetAttribute((const void*)k_gemm256,
                      hipFuncAttributeMaxDynamicSharedMemorySize, 131072);

  k_prep_x  <<<25600, 256, 0, stream>>>(x, pos, XP);
  k_prep_w  <<<2048, 256, 0, stream>>>(Win, Wg, W2);
  k_prep_wbc<<<24, 256, 0, stream>>>(WB, WC, WBb, WCb);
  k_gemm256 <<<3200, 512, 131072, stream>>>(XP, W2, WBb, bin, bg, BP);
  k_C       <<<800, 256, 0, stream>>>(XP, WCb, bC, CB);
  k_finB    <<<800, 256, 0, stream>>>(BP, bB, BF);
  k_scan    <<<64, 128, 0, stream>>>(BF, CB, Alog, Yb);
  k_out     <<<1600, 256, 0, stream>>>(Yb, Wout, bout, (float*)d_out);
}